// Round 6
// baseline (250.773 us; speedup 1.0000x reference)
//
#include <hip/hip_runtime.h>
#include <math.h>

#define S 1024
#define DIMM 1024
#define G 4
#define HPG 4
#define HD 64
#define PW 32
#define SCALE 0.125f
#define LNEPS 1e-5f

typedef __bf16 bf16x8 __attribute__((ext_vector_type(8)));
typedef float  f32x4  __attribute__((ext_vector_type(4)));
typedef float  f32x16 __attribute__((ext_vector_type(16)));

// ---------------- fused f32->bf16 conversions + bias concat ----------------
__global__ __launch_bounds__(256)
void cvt_all(const float* __restrict__ x, const float* __restrict__ kv,
             const float* __restrict__ qw, const float* __restrict__ kw,
             const float* __restrict__ vw, const float* __restrict__ ow,
             const float* __restrict__ kb, const float* __restrict__ vb_,
             __bf16* __restrict__ xh, __bf16* __restrict__ kvh,
             __bf16* __restrict__ qwh, __bf16* __restrict__ kvwh,
             __bf16* __restrict__ owh, __bf16* __restrict__ owl,
             float* __restrict__ kvbias) {
    if (blockIdx.x == 5376) {
        kvbias[threadIdx.x]       = kb[threadIdx.x];
        kvbias[256 + threadIdx.x] = vb_[threadIdx.x];
        return;
    }
    long j = (long)blockIdx.x * 256 + threadIdx.x;
    const float* src; __bf16* dh; __bf16* dl = nullptr;
    if (j < 524288)            { src = x;  dh = xh; }
    else if ((j -= 524288) < 524288) { src = kv; dh = kvh; }
    else if ((j -= 524288) < 131072) { src = qw; dh = qwh; }
    else if ((j -= 131072) < 32768)  { src = kw; dh = kvwh; }
    else if ((j -= 32768) < 32768)   { src = vw; dh = kvwh + 262144; }
    else { j -= 32768; src = ow; dh = owh; dl = owl; }
    const float4 a = *(const float4*)(src + j * 8);
    const float4 b = *(const float4*)(src + j * 8 + 4);
    const float v[8] = {a.x, a.y, a.z, a.w, b.x, b.y, b.z, b.w};
    bf16x8 H;
    #pragma unroll
    for (int e = 0; e < 8; ++e) H[e] = (__bf16)v[e];
    *(bf16x8*)(dh + j * 8) = H;
    if (dl != nullptr) {
        bf16x8 L;
        #pragma unroll
        for (int e = 0; e < 8; ++e) L[e] = (__bf16)(v[e] - (float)H[e]);
        *(bf16x8*)(dl + j * 8) = L;
    }
}

// ---------------- var-id equality masks: mask[b*1024+q][kt] bit j = (qv==kv[kt*64+j])
__global__ __launch_bounds__(256)
void var_mask(const int* __restrict__ qvar, const int* __restrict__ kvar,
              unsigned long long* __restrict__ mask) {
    const int wid  = blockIdx.x * 4 + (threadIdx.x >> 6);   // b*1024 + q
    const int lane = threadIdx.x & 63;
    const int b = wid >> 10;
    const int qv = qvar[wid];
    const int* kb = kvar + (b << 10);
    unsigned long long* mrow = mask + (size_t)wid * 16;
    #pragma unroll 4
    for (int t = 0; t < 16; ++t) {
        const unsigned long long bal = __ballot(qv == kb[t * 64 + lane]);
        if (lane == 0) mrow[t] = bal;
    }
}

// ---------------- bf16 MFMA GEMM (m97 structure) ----------------
__device__ __forceinline__ void gld_lds16(const __bf16* g, __bf16* lds) {
    __builtin_amdgcn_global_load_lds(
        (const __attribute__((address_space(1))) void*)g,
        (__attribute__((address_space(3))) void*)lds, 16, 0, 0);
}

template<int NB, bool SPLIT, bool OUTBF>
__global__ __launch_bounds__(256)
void gemm_mfma(const __bf16* __restrict__ Ah, const __bf16* __restrict__ Al,
               const __bf16* __restrict__ Wh, const __bf16* __restrict__ Wl,
               const float* __restrict__ bias, void* __restrict__ Cout,
               const int N, const int K) {
    constexpr int WN  = NB / 2;
    constexpr int FN  = WN / 16;
    constexpr int NWC = NB / 16;
    __shared__ __bf16 Ahs[128][32];
    __shared__ __bf16 Whs[NB][32];
    __shared__ __bf16 Als[SPLIT ? 128 : 1][32];
    __shared__ __bf16 Wls[SPLIT ? NB : 1][32];

    const int tid = threadIdx.x;
    const int w = tid >> 6, l = tid & 63;
    const int lr = l & 15, lh = l >> 4;
    const int wr = w >> 1, wc = w & 1;
    const int m0 = blockIdx.y * 128, n0 = blockIdx.x * NB;
    const int srow = l >> 2, scol = (l & 3) * 8;

    f32x4 acc[4][FN];
    #pragma unroll
    for (int i = 0; i < 4; ++i)
        #pragma unroll
        for (int j = 0; j < FN; ++j) acc[i][j] = (f32x4){0.f, 0.f, 0.f, 0.f};

    const __bf16* Abp = Ah + (size_t)(m0 + srow) * K + scol;
    const __bf16* Wbp = Wh + (size_t)(n0 + srow) * K + scol;
    const __bf16* Alp = SPLIT ? (Al + (size_t)(m0 + srow) * K + scol) : nullptr;
    const __bf16* Wlp = SPLIT ? (Wl + (size_t)(n0 + srow) * K + scol) : nullptr;

    for (int k0 = 0; k0 < K; k0 += 32) {
        #pragma unroll
        for (int c = 0; c < 2; ++c) {
            const int ch = c * 4 + w;
            gld_lds16(Abp + (size_t)ch * 16 * K + k0, &Ahs[ch * 16][0]);
            if constexpr (SPLIT)
                gld_lds16(Alp + (size_t)ch * 16 * K + k0, &Als[ch * 16][0]);
        }
        #pragma unroll
        for (int c = 0; c < NWC / 4; ++c) {
            const int ch = c * 4 + w;
            gld_lds16(Wbp + (size_t)ch * 16 * K + k0, &Whs[ch * 16][0]);
            if constexpr (SPLIT)
                gld_lds16(Wlp + (size_t)ch * 16 * K + k0, &Wls[ch * 16][0]);
        }
        __syncthreads();

        bf16x8 af[4], bfr[FN];
        #pragma unroll
        for (int i = 0; i < 4; ++i) af[i] = *(const bf16x8*)&Ahs[wr * 64 + 16 * i + lr][lh * 8];
        #pragma unroll
        for (int j = 0; j < FN; ++j) bfr[j] = *(const bf16x8*)&Whs[wc * WN + 16 * j + lr][lh * 8];
        #pragma unroll
        for (int i = 0; i < 4; ++i)
            #pragma unroll
            for (int j = 0; j < FN; ++j)
                acc[i][j] = __builtin_amdgcn_mfma_f32_16x16x32_bf16(af[i], bfr[j], acc[i][j], 0, 0, 0);
        if constexpr (SPLIT) {
            bf16x8 al8[4], wl8[FN];
            #pragma unroll
            for (int i = 0; i < 4; ++i) al8[i] = *(const bf16x8*)&Als[wr * 64 + 16 * i + lr][lh * 8];
            #pragma unroll
            for (int j = 0; j < FN; ++j) wl8[j] = *(const bf16x8*)&Wls[wc * WN + 16 * j + lr][lh * 8];
            #pragma unroll
            for (int i = 0; i < 4; ++i)
                #pragma unroll
                for (int j = 0; j < FN; ++j) {
                    acc[i][j] = __builtin_amdgcn_mfma_f32_16x16x32_bf16(al8[i], bfr[j], acc[i][j], 0, 0, 0);
                    acc[i][j] = __builtin_amdgcn_mfma_f32_16x16x32_bf16(af[i], wl8[j], acc[i][j], 0, 0, 0);
                }
        }
        __syncthreads();
    }

    float bv[FN];
    #pragma unroll
    for (int j = 0; j < FN; ++j) bv[j] = bias[n0 + wc * WN + 16 * j + lr];
    #pragma unroll
    for (int i = 0; i < 4; ++i) {
        const int mb = m0 + wr * 64 + 16 * i + 4 * lh;
        #pragma unroll
        for (int j = 0; j < FN; ++j) {
            const int n = n0 + wc * WN + 16 * j + lr;
            #pragma unroll
            for (int r = 0; r < 4; ++r) {
                const float v = acc[i][j][r] + bv[j];
                if constexpr (OUTBF) ((__bf16*)Cout)[(size_t)(mb + r) * N + n] = (__bf16)v;
                else                 ((float*)Cout)[(size_t)(mb + r) * N + n] = v;
            }
        }
    }
}

// ---------------- wave helpers ----------------
__device__ inline float wave64_sum(float v) {
    #pragma unroll
    for (int off = 32; off >= 1; off >>= 1) v += __shfl_xor(v, off);
    return v;
}

// ---------------- q: LayerNorm + rotary -> bf16 [bgh][s][d] ----------------
__global__ __launch_bounds__(256)
void q_transform(const __bf16* __restrict__ q_lin, const float* __restrict__ gam,
                 const float* __restrict__ bet, const int* __restrict__ t_id,
                 __bf16* __restrict__ q_n) {
    const int row  = blockIdx.x * 4 + (threadIdx.x >> 6);
    const int lane = threadIdx.x & 63;
    const int s    = row & (S - 1);
    const int bgh  = row >> 10;
    const int b    = bgh >> 4;
    const int gh   = bgh & 15;
    float x = (float)q_lin[(size_t)(b * S + s) * DIMM + gh * HD + lane];
    const float m = wave64_sum(x) * (1.0f / 64.0f);
    const float d = x - m;
    const float v = wave64_sum(d * d) * (1.0f / 64.0f);
    float y = d * rsqrtf(v + LNEPS) * gam[lane] + bet[lane];
    const float partner = __shfl_xor(y, 1);
    if (lane < PW) {
        const int i = lane >> 1;
        const float theta = expf(-0.57564627324851f * (float)i);
        const float ang = (float)t_id[b * S + s] * theta;
        const float cs = cosf(ang), sn = sinf(ang);
        y = cs * y + sn * ((lane & 1) ? partner : -partner);
    }
    q_n[(size_t)row * HD + lane] = (__bf16)y;
}

// ---------------- k: LayerNorm + rotary -> bf16 [bg][s][d] ----------------
__global__ __launch_bounds__(256)
void k_transform(const __bf16* __restrict__ kv_lin, const float* __restrict__ gam,
                 const float* __restrict__ bet, const int* __restrict__ t_id,
                 __bf16* __restrict__ k_n) {
    const int row  = blockIdx.x * 4 + (threadIdx.x >> 6);
    const int lane = threadIdx.x & 63;
    const int s    = row & (S - 1);
    const int bg   = row >> 10;
    const int b    = bg >> 2;
    const int g    = bg & 3;
    float x = (float)kv_lin[(size_t)(b * S + s) * 512 + g * HD + lane];
    const float m = wave64_sum(x) * (1.0f / 64.0f);
    const float d = x - m;
    const float v = wave64_sum(d * d) * (1.0f / 64.0f);
    float y = d * rsqrtf(v + LNEPS) * gam[lane] + bet[lane];
    const float partner = __shfl_xor(y, 1);
    if (lane < PW) {
        const int i = lane >> 1;
        const float theta = expf(-0.57564627324851f * (float)i);
        const float ang = (float)t_id[b * S + s] * theta;
        const float cs = cosf(ang), sn = sinf(ang);
        y = cs * y + sn * ((lane & 1) ? partner : -partner);
    }
    k_n[(size_t)row * HD + lane] = (__bf16)y;
}

// ---------------- V transpose: bf16 kv_lin[b][s][256+g*64+d] -> bf16 [bg][d][s] ----
__global__ __launch_bounds__(256)
void v_transpose(const __bf16* __restrict__ kv_lin, __bf16* __restrict__ vt) {
    __shared__ float T[64][65];
    const int bg = blockIdx.x >> 4;
    const int s0 = (blockIdx.x & 15) * 64;
    const int b = bg >> 2, g = bg & 3;
    const int tx = threadIdx.x & 63, ty = threadIdx.x >> 6;
    const __bf16* src = kv_lin + ((size_t)(b * S) + s0) * 512 + 256 + g * HD;
    #pragma unroll
    for (int i = 0; i < 16; ++i) {
        const int sp = ty + 4 * i;
        T[sp][tx] = (float)src[(size_t)sp * 512 + tx];
    }
    __syncthreads();
    __bf16* dst = vt + (size_t)bg * HD * S + s0;
    #pragma unroll
    for (int i = 0; i < 16; ++i) {
        const int d = ty + 4 * i;
        dst[(size_t)d * S + tx] = (__bf16)T[tx][d];
    }
}

// ---------------- flash attention v4: 32x32 swapped, K-split x2, mask bias ----
// block = 4 waves = 2 q-groups x 2 K-halves; LDS merge of (m,l,O) at the end.
__global__ __launch_bounds__(256, 4)
void flash_mfma(const __bf16* __restrict__ q_n, const __bf16* __restrict__ k_n,
                const __bf16* __restrict__ vt, const float* __restrict__ var_emb,
                const unsigned long long* __restrict__ vmask,
                __bf16* __restrict__ attn_h, __bf16* __restrict__ attn_l) {
    __shared__ f32x4 Osh[2][8][64];
    __shared__ float mlsh[2][2][64];

    const int tid = threadIdx.x;
    const int w = tid >> 6, l = tid & 63;
    const int lq = l & 31;
    const int h  = l >> 5;
    const int qhalf = w >> 1, khalf = w & 1;
    const int qb  = blockIdx.x & 15;
    const int bgh = blockIdx.x >> 4;
    const int b = bgh >> 4, gh = bgh & 15;
    const int bg = bgh >> 2;
    const int q0 = qb * 64 + qhalf * 32;
    const int kbeg = khalf * 512;

    // Q B-frags: lane holds Q[q=lq][d = 16*dc + 8*h + e]
    const __bf16* qbase = q_n + ((size_t)bgh * S + q0 + lq) * HD + 8 * h;
    bf16x8 qf[4];
    #pragma unroll
    for (int dc = 0; dc < 4; ++dc) qf[dc] = *(const bf16x8*)(qbase + 16 * dc);

    constexpr float L2E = 1.4426950408889634f;
    const float w0l = var_emb[gh] * L2E;
    const float dwl = (var_emb[16 + gh] - var_emb[gh]) * L2E;
    const float sc2 = SCALE * L2E;

    const __bf16* kbase = k_n + (size_t)bg * S * HD;
    const __bf16* vbase = vt + (size_t)bg * HD * S;
    const unsigned long long* mrow = vmask + ((size_t)(b << 10) + q0 + lq) * 16;

    f32x16 OT[2];
    #pragma unroll
    for (int t = 0; t < 2; ++t)
        #pragma unroll
        for (int r = 0; r < 16; ++r) OT[t][r] = 0.0f;
    float mrun = -3.0e38f, lrun = 0.0f;

    // preload K tile + mask for kbeg
    bf16x8 kf[2][4];
    #pragma unroll
    for (int ks = 0; ks < 2; ++ks)
        #pragma unroll
        for (int dc = 0; dc < 4; ++dc)
            kf[ks][dc] = *(const bf16x8*)(kbase + (size_t)(kbeg + 32 * ks + lq) * HD + 16 * dc + 8 * h);
    unsigned long long Mcur = mrow[kbeg >> 6] >> (4 * h);

    for (int k0 = kbeg; k0 < kbeg + 512; k0 += 64) {
        // V A-frags for current tile
        bf16x8 vf[2][2][2];
        #pragma unroll
        for (int t = 0; t < 2; ++t)
            #pragma unroll
            for (int ks = 0; ks < 2; ++ks)
                #pragma unroll
                for (int kc = 0; kc < 2; ++kc)
                    vf[t][ks][kc] = *(const bf16x8*)
                        (vbase + (size_t)(32 * t + lq) * S + k0 + 32 * ks + 16 * kc + 8 * h);

        // swapped QK^T: lane gets S[k = 32ks + (r&3)+8(r>>2)+4h][q=lq]
        f32x16 st[2];
        #pragma unroll
        for (int ks = 0; ks < 2; ++ks) {
            f32x16 acc;
            #pragma unroll
            for (int r = 0; r < 16; ++r) acc[r] = 0.0f;
            #pragma unroll
            for (int dc = 0; dc < 4; ++dc)
                acc = __builtin_amdgcn_mfma_f32_32x32x16_bf16(kf[ks][dc], qf[dc], acc, 0, 0, 0);
            st[ks] = acc;
        }

        // prefetch next K tile + mask (wrap to kbeg at end; harmless reload)
        const int kn = (k0 + 64 < kbeg + 512) ? k0 + 64 : kbeg;
        #pragma unroll
        for (int ks = 0; ks < 2; ++ks)
            #pragma unroll
            for (int dc = 0; dc < 4; ++dc)
                kf[ks][dc] = *(const bf16x8*)
                    (kbase + (size_t)(kn + 32 * ks + lq) * HD + 16 * dc + 8 * h);
        const unsigned long long Mnext = mrow[kn >> 6] >> (4 * h);

        // bias (from mask bits) + scale + in-lane max
        const unsigned mlo = (unsigned)Mcur;
        const unsigned mhi = (unsigned)(Mcur >> 32);
        float tmax = -3.0e38f;
        #pragma unroll
        for (int ks = 0; ks < 2; ++ks) {
            const unsigned wm = ks ? mhi : mlo;
            #pragma unroll
            for (int r = 0; r < 16; ++r) {
                const int jr = (r & 3) + 8 * (r >> 2);
                const float bias = fmaf((float)((wm >> jr) & 1u), dwl, w0l);
                st[ks][r] = fmaf(st[ks][r], sc2, bias);
                tmax = fmaxf(tmax, st[ks][r]);
            }
        }
        tmax = fmaxf(tmax, __shfl_xor(tmax, 32));

        // defer-max (THR = 8 nats = 11.54 log2)
        float mref = mrun;
        if (!__all(tmax - mrun <= 11.54f)) {
            const float mnew = fmaxf(mrun, tmax);
            const float alpha = exp2f(mrun - mnew);
            #pragma unroll
            for (int t = 0; t < 2; ++t)
                #pragma unroll
                for (int r = 0; r < 16; ++r) OT[t][r] *= alpha;
            lrun *= alpha;
            mrun = mnew; mref = mnew;
        }

        // P = exp2(st - mref); pack pairs to bf16
        float psum = 0.0f;
        unsigned int u[2][8];
        #pragma unroll
        for (int ks = 0; ks < 2; ++ks)
            #pragma unroll
            for (int jj = 0; jj < 8; ++jj) {
                const float p0 = exp2f(st[ks][2 * jj]     - mref);
                const float p1 = exp2f(st[ks][2 * jj + 1] - mref);
                psum += p0 + p1;
                asm("v_cvt_pk_bf16_f32 %0, %1, %2" : "=v"(u[ks][jj]) : "v"(p0), "v"(p1));
            }
        psum += __shfl_xor(psum, 32);
        lrun += psum;

        // P redistribution via permlane32_swap -> B-frag words
        uint4 F[2][2];
        #pragma unroll
        for (int ks = 0; ks < 2; ++ks) {
            unsigned a0 = u[ks][0], b0 = u[ks][2];
            unsigned a1 = u[ks][1], b1 = u[ks][3];
            asm("v_permlane32_swap_b32 %0, %1" : "+v"(a0), "+v"(b0));
            asm("v_permlane32_swap_b32 %0, %1" : "+v"(a1), "+v"(b1));
            F[ks][0] = make_uint4(a0, a1, b0, b1);
            unsigned a2 = u[ks][4], b2 = u[ks][6];
            unsigned a3 = u[ks][5], b3 = u[ks][7];
            asm("v_permlane32_swap_b32 %0, %1" : "+v"(a2), "+v"(b2));
            asm("v_permlane32_swap_b32 %0, %1" : "+v"(a3), "+v"(b3));
            F[ks][1] = make_uint4(a2, a3, b2, b3);
        }

        // PV: O^T[d][q] += V^T[d][k] * P^T[k][q]
        #pragma unroll
        for (int t = 0; t < 2; ++t)
            #pragma unroll
            for (int ks = 0; ks < 2; ++ks)
                #pragma unroll
                for (int kc = 0; kc < 2; ++kc)
                    OT[t] = __builtin_amdgcn_mfma_f32_32x32x16_bf16(
                        vf[t][ks][kc], __builtin_bit_cast(bf16x8, F[ks][kc]), OT[t], 0, 0, 0);

        Mcur = Mnext;
    }

    // ---- merge the two K-halves (lane-local per q) ----
    if (khalf) {
        #pragma unroll
        for (int t = 0; t < 2; ++t)
            #pragma unroll
            for (int c = 0; c < 4; ++c)
                Osh[qhalf][t * 4 + c][l] = (f32x4){OT[t][4 * c], OT[t][4 * c + 1],
                                                   OT[t][4 * c + 2], OT[t][4 * c + 3]};
        mlsh[qhalf][0][l] = mrun;
        mlsh[qhalf][1][l] = lrun;
    }
    __syncthreads();
    if (khalf) return;

    const float mb2 = mlsh[qhalf][0][l];
    const float lb2 = mlsh[qhalf][1][l];
    const float mm = fmaxf(mrun, mb2);
    const float sa = exp2f(mrun - mm);
    const float sb = exp2f(mb2 - mm);
    const float linv = 1.0f / (lrun * sa + lb2 * sb);

    __bf16* oh = attn_h + (size_t)(b * S + q0 + lq) * DIMM + gh * HD;
    __bf16* ol = attn_l + (size_t)(b * S + q0 + lq) * DIMM + gh * HD;
    #pragma unroll
    for (int t = 0; t < 2; ++t)
        #pragma unroll
        for (int j = 0; j < 4; ++j) {
            const f32x4 ob = Osh[qhalf][t * 4 + j][l];
            const int d0 = 32 * t + 8 * j + 4 * h;
            unsigned short hv[4], lv[4];
            #pragma unroll
            for (int c = 0; c < 4; ++c) {
                const float v = (OT[t][4 * j + c] * sa + ob[c] * sb) * linv;
                const __bf16 hb = (__bf16)v;
                hv[c] = __builtin_bit_cast(unsigned short, hb);
                lv[c] = __builtin_bit_cast(unsigned short, (__bf16)(v - (float)hb));
            }
            *(ushort4*)(oh + d0) = make_ushort4(hv[0], hv[1], hv[2], hv[3]);
            *(ushort4*)(ol + d0) = make_ushort4(lv[0], lv[1], lv[2], lv[3]);
        }
}

extern "C" void kernel_launch(void* const* d_in, const int* in_sizes, int n_in,
                              void* d_out, int out_size, void* d_ws, size_t ws_size,
                              hipStream_t stream) {
    const float* x     = (const float*)d_in[0];
    const float* kv    = (const float*)d_in[1];
    const float* q_w   = (const float*)d_in[2];
    const float* q_b   = (const float*)d_in[3];
    const float* k_w   = (const float*)d_in[4];
    const float* k_b   = (const float*)d_in[5];
    const float* v_w   = (const float*)d_in[6];
    const float* v_b   = (const float*)d_in[7];
    const float* o_w   = (const float*)d_in[8];
    const float* o_b   = (const float*)d_in[9];
    const float* qn_g  = (const float*)d_in[10];
    const float* qn_b  = (const float*)d_in[11];
    const float* kn_g  = (const float*)d_in[12];
    const float* kn_b  = (const float*)d_in[13];
    const float* vemb  = (const float*)d_in[14];
    const int*   qvar  = (const int*)d_in[15];
    const int*   kvar  = (const int*)d_in[16];
    const int*   qtime = (const int*)d_in[17];
    const int*   ktime = (const int*)d_in[18];
    float* out = (float*)d_out;
    char*  W   = (char*)d_ws;

    const size_t MB = 1u << 20;
    __bf16* xh     = (__bf16*)(W);                 // 0-8   -> attn_h
    __bf16* kvh    = (__bf16*)(W + 8 * MB);        // 8-16  -> attn_l
    __bf16* q_lin  = (__bf16*)(W + 16 * MB);       // 16-24 (dead after q_transform)
    __bf16* kv_lin = (__bf16*)(W + 24 * MB);       // 24-28 (dead after k_t/v_t)
    unsigned long long* vmask = (unsigned long long*)(W + 16 * MB);  // reuse q_lin, 512KB
    __bf16* q_nb   = (__bf16*)(W + 28 * MB);       // 28-36 (overlays qwh/kvwh/kvb)
    __bf16* qwh    = (__bf16*)(W + 28 * MB);
    __bf16* kvwh   = (__bf16*)(W + 30 * MB);
    float*  kvb    = (float*)(W + 31 * MB);
    __bf16* k_nb   = (__bf16*)(W + 36 * MB);       // 36-38
    __bf16* vtb    = (__bf16*)(W + 38 * MB);       // 38-40
    __bf16* owh    = (__bf16*)(W + 40 * MB);       // 40-42
    __bf16* owl    = (__bf16*)(W + 42 * MB);       // 42-44
    __bf16* attn_h = xh;
    __bf16* attn_l = kvh;

    dim3 blk(256);

    cvt_all<<<5377, blk, 0, stream>>>(x, kv, q_w, k_w, v_w, o_w, k_b, v_b,
                                      xh, kvh, qwh, kvwh, owh, owl, kvb);

    gemm_mfma<64, false, true><<<dim3(16, 32), blk, 0, stream>>>(
        xh, nullptr, qwh, nullptr, q_b, (void*)q_lin, 1024, 1024);
    gemm_mfma<64, false, true><<<dim3(8, 32), blk, 0, stream>>>(
        kvh, nullptr, kvwh, nullptr, kvb, (void*)kv_lin, 512, 1024);

    q_transform<<<(4 * G * HPG * S) / 4, blk, 0, stream>>>(q_lin, qn_g, qn_b, qtime, q_nb);
    k_transform<<<(4 * G * S) / 4,       blk, 0, stream>>>(kv_lin, kn_g, kn_b, ktime, k_nb);
    v_transpose<<<16 * 16,               blk, 0, stream>>>(kv_lin, vtb);

    var_mask<<<1024, blk, 0, stream>>>(qvar, kvar, vmask);   // q_lin dead by now

    flash_mfma<<<64 * 16, blk, 0, stream>>>(
        q_nb, k_nb, vtb, vemb, vmask, attn_h, attn_l);

    gemm_mfma<64, true, false><<<dim3(16, 32), blk, 0, stream>>>(
        attn_h, attn_l, owh, owl, o_b, (void*)out, 1024, 1024);
}

// Round 7
// 163.521 us; speedup vs baseline: 1.5336x; 1.5336x over previous
//
#include <hip/hip_runtime.h>
#include <math.h>

#define S 1024
#define DIMM 1024
#define G 4
#define HPG 4
#define HD 64
#define PW 32
#define SCALE 0.125f
#define LNEPS 1e-5f

typedef __bf16 bf16x8 __attribute__((ext_vector_type(8)));
typedef float  f32x4  __attribute__((ext_vector_type(4)));
typedef float  f32x16 __attribute__((ext_vector_type(16)));

// ---------------- fused f32->bf16 conversions + bias concat ----------------
__global__ __launch_bounds__(256)
void cvt_all(const float* __restrict__ x, const float* __restrict__ kv,
             const float* __restrict__ qw, const float* __restrict__ kw,
             const float* __restrict__ vw, const float* __restrict__ ow,
             const float* __restrict__ kb, const float* __restrict__ vb_,
             __bf16* __restrict__ xh, __bf16* __restrict__ kvh,
             __bf16* __restrict__ qwh, __bf16* __restrict__ kvwh,
             __bf16* __restrict__ owh, __bf16* __restrict__ owl,
             float* __restrict__ kvbias) {
    if (blockIdx.x == 5376) {
        kvbias[threadIdx.x]       = kb[threadIdx.x];
        kvbias[256 + threadIdx.x] = vb_[threadIdx.x];
        return;
    }
    long j = (long)blockIdx.x * 256 + threadIdx.x;
    const float* src; __bf16* dh; __bf16* dl = nullptr;
    if (j < 524288)            { src = x;  dh = xh; }
    else if ((j -= 524288) < 524288) { src = kv; dh = kvh; }
    else if ((j -= 524288) < 131072) { src = qw; dh = qwh; }
    else if ((j -= 131072) < 32768)  { src = kw; dh = kvwh; }
    else if ((j -= 32768) < 32768)   { src = vw; dh = kvwh + 262144; }
    else { j -= 32768; src = ow; dh = owh; dl = owl; }
    const float4 a = *(const float4*)(src + j * 8);
    const float4 b = *(const float4*)(src + j * 8 + 4);
    const float v[8] = {a.x, a.y, a.z, a.w, b.x, b.y, b.z, b.w};
    bf16x8 H;
    #pragma unroll
    for (int e = 0; e < 8; ++e) H[e] = (__bf16)v[e];
    *(bf16x8*)(dh + j * 8) = H;
    if (dl != nullptr) {
        bf16x8 L;
        #pragma unroll
        for (int e = 0; e < 8; ++e) L[e] = (__bf16)(v[e] - (float)H[e]);
        *(bf16x8*)(dl + j * 8) = L;
    }
}

// ---------------- var-id equality masks, transposed: mask[(b*16+kt)*1024+q] ----
__global__ __launch_bounds__(256)
void var_mask(const int* __restrict__ qvar, const int* __restrict__ kvar,
              unsigned long long* __restrict__ mask) {
    const int wid  = blockIdx.x * 4 + (threadIdx.x >> 6);   // b*1024 + q
    const int lane = threadIdx.x & 63;
    const int b = wid >> 10;
    const int q = wid & 1023;
    const int qv = qvar[wid];
    const int* kb = kvar + (b << 10);
    #pragma unroll 4
    for (int t = 0; t < 16; ++t) {
        const unsigned long long bal = __ballot(qv == kb[t * 64 + lane]);
        if (lane == 0) mask[(size_t)(b * 16 + t) * 1024 + q] = bal;
    }
}

// ---------------- bf16 MFMA GEMM (m97 structure) ----------------
__device__ __forceinline__ void gld_lds16(const __bf16* g, __bf16* lds) {
    __builtin_amdgcn_global_load_lds(
        (const __attribute__((address_space(1))) void*)g,
        (__attribute__((address_space(3))) void*)lds, 16, 0, 0);
}

template<int NB, bool SPLIT, bool OUTBF>
__global__ __launch_bounds__(256)
void gemm_mfma(const __bf16* __restrict__ Ah, const __bf16* __restrict__ Al,
               const __bf16* __restrict__ Wh, const __bf16* __restrict__ Wl,
               const float* __restrict__ bias, void* __restrict__ Cout,
               const int N, const int K) {
    constexpr int WN  = NB / 2;
    constexpr int FN  = WN / 16;
    constexpr int NWC = NB / 16;
    __shared__ __bf16 Ahs[128][32];
    __shared__ __bf16 Whs[NB][32];
    __shared__ __bf16 Als[SPLIT ? 128 : 1][32];
    __shared__ __bf16 Wls[SPLIT ? NB : 1][32];

    const int tid = threadIdx.x;
    const int w = tid >> 6, l = tid & 63;
    const int lr = l & 15, lh = l >> 4;
    const int wr = w >> 1, wc = w & 1;
    const int m0 = blockIdx.y * 128, n0 = blockIdx.x * NB;
    const int srow = l >> 2, scol = (l & 3) * 8;

    f32x4 acc[4][FN];
    #pragma unroll
    for (int i = 0; i < 4; ++i)
        #pragma unroll
        for (int j = 0; j < FN; ++j) acc[i][j] = (f32x4){0.f, 0.f, 0.f, 0.f};

    const __bf16* Abp = Ah + (size_t)(m0 + srow) * K + scol;
    const __bf16* Wbp = Wh + (size_t)(n0 + srow) * K + scol;
    const __bf16* Alp = SPLIT ? (Al + (size_t)(m0 + srow) * K + scol) : nullptr;
    const __bf16* Wlp = SPLIT ? (Wl + (size_t)(n0 + srow) * K + scol) : nullptr;

    for (int k0 = 0; k0 < K; k0 += 32) {
        #pragma unroll
        for (int c = 0; c < 2; ++c) {
            const int ch = c * 4 + w;
            gld_lds16(Abp + (size_t)ch * 16 * K + k0, &Ahs[ch * 16][0]);
            if constexpr (SPLIT)
                gld_lds16(Alp + (size_t)ch * 16 * K + k0, &Als[ch * 16][0]);
        }
        #pragma unroll
        for (int c = 0; c < NWC / 4; ++c) {
            const int ch = c * 4 + w;
            gld_lds16(Wbp + (size_t)ch * 16 * K + k0, &Whs[ch * 16][0]);
            if constexpr (SPLIT)
                gld_lds16(Wlp + (size_t)ch * 16 * K + k0, &Wls[ch * 16][0]);
        }
        __syncthreads();

        bf16x8 af[4], bfr[FN];
        #pragma unroll
        for (int i = 0; i < 4; ++i) af[i] = *(const bf16x8*)&Ahs[wr * 64 + 16 * i + lr][lh * 8];
        #pragma unroll
        for (int j = 0; j < FN; ++j) bfr[j] = *(const bf16x8*)&Whs[wc * WN + 16 * j + lr][lh * 8];
        #pragma unroll
        for (int i = 0; i < 4; ++i)
            #pragma unroll
            for (int j = 0; j < FN; ++j)
                acc[i][j] = __builtin_amdgcn_mfma_f32_16x16x32_bf16(af[i], bfr[j], acc[i][j], 0, 0, 0);
        if constexpr (SPLIT) {
            bf16x8 al8[4], wl8[FN];
            #pragma unroll
            for (int i = 0; i < 4; ++i) al8[i] = *(const bf16x8*)&Als[wr * 64 + 16 * i + lr][lh * 8];
            #pragma unroll
            for (int j = 0; j < FN; ++j) wl8[j] = *(const bf16x8*)&Wls[wc * WN + 16 * j + lr][lh * 8];
            #pragma unroll
            for (int i = 0; i < 4; ++i)
                #pragma unroll
                for (int j = 0; j < FN; ++j) {
                    acc[i][j] = __builtin_amdgcn_mfma_f32_16x16x32_bf16(al8[i], bfr[j], acc[i][j], 0, 0, 0);
                    acc[i][j] = __builtin_amdgcn_mfma_f32_16x16x32_bf16(af[i], wl8[j], acc[i][j], 0, 0, 0);
                }
        }
        __syncthreads();
    }

    float bv[FN];
    #pragma unroll
    for (int j = 0; j < FN; ++j) bv[j] = bias[n0 + wc * WN + 16 * j + lr];
    #pragma unroll
    for (int i = 0; i < 4; ++i) {
        const int mb = m0 + wr * 64 + 16 * i + 4 * lh;
        #pragma unroll
        for (int j = 0; j < FN; ++j) {
            const int n = n0 + wc * WN + 16 * j + lr;
            #pragma unroll
            for (int r = 0; r < 4; ++r) {
                const float v = acc[i][j][r] + bv[j];
                if constexpr (OUTBF) ((__bf16*)Cout)[(size_t)(mb + r) * N + n] = (__bf16)v;
                else                 ((float*)Cout)[(size_t)(mb + r) * N + n] = v;
            }
        }
    }
}

// ---------------- wave helpers ----------------
__device__ inline float wave64_sum(float v) {
    #pragma unroll
    for (int off = 32; off >= 1; off >>= 1) v += __shfl_xor(v, off);
    return v;
}

// ---------------- q: LayerNorm + rotary -> bf16 [bgh][s][d] ----------------
__global__ __launch_bounds__(256)
void q_transform(const __bf16* __restrict__ q_lin, const float* __restrict__ gam,
                 const float* __restrict__ bet, const int* __restrict__ t_id,
                 __bf16* __restrict__ q_n) {
    const int row  = blockIdx.x * 4 + (threadIdx.x >> 6);
    const int lane = threadIdx.x & 63;
    const int s    = row & (S - 1);
    const int bgh  = row >> 10;
    const int b    = bgh >> 4;
    const int gh   = bgh & 15;
    float x = (float)q_lin[(size_t)(b * S + s) * DIMM + gh * HD + lane];
    const float m = wave64_sum(x) * (1.0f / 64.0f);
    const float d = x - m;
    const float v = wave64_sum(d * d) * (1.0f / 64.0f);
    float y = d * rsqrtf(v + LNEPS) * gam[lane] + bet[lane];
    const float partner = __shfl_xor(y, 1);
    if (lane < PW) {
        const int i = lane >> 1;
        const float theta = expf(-0.57564627324851f * (float)i);
        const float ang = (float)t_id[b * S + s] * theta;
        const float cs = cosf(ang), sn = sinf(ang);
        y = cs * y + sn * ((lane & 1) ? partner : -partner);
    }
    q_n[(size_t)row * HD + lane] = (__bf16)y;
}

// ---------------- k: LayerNorm + rotary -> bf16 FRAGMENT-MAJOR layout --------
// kfrag flat idx = ((bg*16+kt)*8 + ks*4 + dc)*512 + h*256 + lq*8 + e
//   where s = 64kt+32ks+lq, d = 16dc+8h+e
__global__ __launch_bounds__(256)
void k_transform(const __bf16* __restrict__ kv_lin, const float* __restrict__ gam,
                 const float* __restrict__ bet, const int* __restrict__ t_id,
                 __bf16* __restrict__ kfrag) {
    const int row  = blockIdx.x * 4 + (threadIdx.x >> 6);
    const int lane = threadIdx.x & 63;
    const int s    = row & (S - 1);
    const int bg   = row >> 10;
    const int b    = bg >> 2;
    const int g    = bg & 3;
    float x = (float)kv_lin[(size_t)(b * S + s) * 512 + g * HD + lane];
    const float m = wave64_sum(x) * (1.0f / 64.0f);
    const float d = x - m;
    const float v = wave64_sum(d * d) * (1.0f / 64.0f);
    float y = d * rsqrtf(v + LNEPS) * gam[lane] + bet[lane];
    const float partner = __shfl_xor(y, 1);
    if (lane < PW) {
        const int i = lane >> 1;
        const float theta = expf(-0.57564627324851f * (float)i);
        const float ang = (float)t_id[b * S + s] * theta;
        const float cs = cosf(ang), sn = sinf(ang);
        y = cs * y + sn * ((lane & 1) ? partner : -partner);
    }
    const size_t idx = (size_t)(((bg * 16 + (s >> 6)) * 8 + ((s >> 5) & 1) * 4
                                 + (lane >> 4)) * 512)
                     + ((lane >> 3) & 1) * 256 + (s & 31) * 8 + (lane & 7);
    kfrag[idx] = (__bf16)y;
}

// ---------------- V -> fragment-major: vfrag[((bg*16+kt)*2+t)*4+ks*2+kc][...] ----
// flat idx = (((bg*16+kt)*2+t)*4 + ks*2 + kc)*512 + h*256 + lq*8 + e
//   holding V element (d = 32t+lq, k = 64kt+32ks+16kc+8h+e)
__global__ __launch_bounds__(256)
void v_frag_k(const __bf16* __restrict__ kv_lin, __bf16* __restrict__ vfrag) {
    __shared__ float T[64][65];   // T[k_local][d]
    const int bg = blockIdx.x >> 4;
    const int kt = blockIdx.x & 15;
    const int b = bg >> 2, g = bg & 3;
    const int tx = threadIdx.x & 63, ty = threadIdx.x >> 6;
    const __bf16* src = kv_lin + ((size_t)(b * S) + kt * 64) * 512 + 256 + g * HD;
    #pragma unroll
    for (int i = 0; i < 16; ++i) {
        const int kl = ty + 4 * i;
        T[kl][tx] = (float)src[(size_t)kl * 512 + tx];
    }
    __syncthreads();
    __bf16* dst = vfrag + (size_t)bg * 65536 + (size_t)kt * 4096;
    #pragma unroll
    for (int half = 0; half < 2; ++half) {
        const int c  = half * 256 + threadIdx.x;
        const int lq = c & 31;
        const int h  = (c >> 5) & 1;
        const int kc = (c >> 6) & 1;
        const int ks = (c >> 7) & 1;
        const int t  = (c >> 8) & 1;
        const int kl = 32 * ks + 16 * kc + 8 * h;
        const int d  = 32 * t + lq;
        bf16x8 o;
        #pragma unroll
        for (int e = 0; e < 8; ++e) o[e] = (__bf16)T[kl + e][d];
        *(bf16x8*)(dst + ((size_t)((t * 2 + ks) * 2 + kc) * 2 + h) * 256 + lq * 8) = o;
    }
}

// ---------------- flash attention v5: frag-major loads, K-split x2 ----------
__global__ __launch_bounds__(256, 2)
void flash_mfma(const __bf16* __restrict__ q_n, const __bf16* __restrict__ kfrag,
                const __bf16* __restrict__ vfrag, const float* __restrict__ var_emb,
                const unsigned long long* __restrict__ vmask,
                __bf16* __restrict__ attn_h, __bf16* __restrict__ attn_l) {
    __shared__ f32x4 Osh[2][8][64];
    __shared__ float mlsh[2][2][64];

    const int tid = threadIdx.x;
    const int w = tid >> 6, l = tid & 63;
    const int lq = l & 31;
    const int h  = l >> 5;
    const int qhalf = w >> 1, khalf = w & 1;
    const int qb  = blockIdx.x & 15;
    const int bgh = blockIdx.x >> 4;
    const int b = bgh >> 4, gh = bgh & 15;
    const int bg = bgh >> 2;
    const int q0 = qb * 64 + qhalf * 32;
    const int ktbeg = khalf * 8;              // first k-tile (of 16)

    // Q B-frags: lane holds Q[q=lq][d = 16*dc + 8*h + e]  (once per wave)
    const __bf16* qbase = q_n + ((size_t)bgh * S + q0 + lq) * HD + 8 * h;
    bf16x8 qf[4];
    #pragma unroll
    for (int dc = 0; dc < 4; ++dc) qf[dc] = *(const bf16x8*)(qbase + 16 * dc);

    constexpr float L2E = 1.4426950408889634f;
    const float w0l = var_emb[gh] * L2E;
    const float dwl = (var_emb[16 + gh] - var_emb[gh]) * L2E;
    const float sc2 = SCALE * L2E;

    // fragment bases (lane offset folded in): every load is one coalesced 1KB burst
    const __bf16* kfr = kfrag + (size_t)bg * 65536 + (size_t)l * 8;
    const __bf16* vfr = vfrag + (size_t)bg * 65536 + (size_t)l * 8;
    const unsigned long long* mbase = vmask + (size_t)(b << 14) + q0 + lq;

    f32x16 OT[2];
    #pragma unroll
    for (int t = 0; t < 2; ++t)
        #pragma unroll
        for (int r = 0; r < 16; ++r) OT[t][r] = 0.0f;
    float mrun = -3.0e38f, lrun = 0.0f;

    // preload K tile ktbeg + its mask
    bf16x8 kf[2][4];
    #pragma unroll
    for (int ks = 0; ks < 2; ++ks)
        #pragma unroll
        for (int dc = 0; dc < 4; ++dc)
            kf[ks][dc] = *(const bf16x8*)(kfr + (size_t)(ktbeg * 8 + ks * 4 + dc) * 512);
    unsigned long long Mcur = mbase[(size_t)ktbeg << 10] >> (4 * h);

    for (int kt = ktbeg; kt < ktbeg + 8; ++kt) {
        // V A-frags for current tile (coalesced)
        bf16x8 vf[2][2][2];
        #pragma unroll
        for (int t = 0; t < 2; ++t)
            #pragma unroll
            for (int ks = 0; ks < 2; ++ks)
                #pragma unroll
                for (int kc = 0; kc < 2; ++kc)
                    vf[t][ks][kc] = *(const bf16x8*)
                        (vfr + (size_t)(((kt * 2 + t) * 2 + ks) * 2 + kc) * 512);

        // swapped QK^T: lane gets S[k = 64kt + 32ks + (r&3)+8(r>>2)+4h][q=lq]
        f32x16 st[2];
        #pragma unroll
        for (int ks = 0; ks < 2; ++ks) {
            f32x16 acc;
            #pragma unroll
            for (int r = 0; r < 16; ++r) acc[r] = 0.0f;
            #pragma unroll
            for (int dc = 0; dc < 4; ++dc)
                acc = __builtin_amdgcn_mfma_f32_32x32x16_bf16(kf[ks][dc], qf[dc], acc, 0, 0, 0);
            st[ks] = acc;
        }

        // prefetch next K tile + mask
        const int kn = (kt + 1 < ktbeg + 8) ? kt + 1 : ktbeg;
        #pragma unroll
        for (int ks = 0; ks < 2; ++ks)
            #pragma unroll
            for (int dc = 0; dc < 4; ++dc)
                kf[ks][dc] = *(const bf16x8*)(kfr + (size_t)(kn * 8 + ks * 4 + dc) * 512);
        const unsigned long long Mnext = mbase[(size_t)kn << 10] >> (4 * h);

        // bias (mask bits) + scale + in-lane max
        const unsigned mlo = (unsigned)Mcur;
        const unsigned mhi = (unsigned)(Mcur >> 32);
        float tmax = -3.0e38f;
        #pragma unroll
        for (int ks = 0; ks < 2; ++ks) {
            const unsigned wm = ks ? mhi : mlo;
            #pragma unroll
            for (int r = 0; r < 16; ++r) {
                const int jr = (r & 3) + 8 * (r >> 2);
                const float bias = fmaf((float)((wm >> jr) & 1u), dwl, w0l);
                st[ks][r] = fmaf(st[ks][r], sc2, bias);
                tmax = fmaxf(tmax, st[ks][r]);
            }
        }
        tmax = fmaxf(tmax, __shfl_xor(tmax, 32));

        // defer-max (THR = 8 nats = 11.54 log2)
        float mref = mrun;
        if (!__all(tmax - mrun <= 11.54f)) {
            const float mnew = fmaxf(mrun, tmax);
            const float alpha = exp2f(mrun - mnew);
            #pragma unroll
            for (int t = 0; t < 2; ++t)
                #pragma unroll
                for (int r = 0; r < 16; ++r) OT[t][r] *= alpha;
            lrun *= alpha;
            mrun = mnew; mref = mnew;
        }

        // P = exp2(st - mref); pack pairs to bf16
        float psum = 0.0f;
        unsigned int u[2][8];
        #pragma unroll
        for (int ks = 0; ks < 2; ++ks)
            #pragma unroll
            for (int jj = 0; jj < 8; ++jj) {
                const float p0 = exp2f(st[ks][2 * jj]     - mref);
                const float p1 = exp2f(st[ks][2 * jj + 1] - mref);
                psum += p0 + p1;
                asm("v_cvt_pk_bf16_f32 %0, %1, %2" : "=v"(u[ks][jj]) : "v"(p0), "v"(p1));
            }
        psum += __shfl_xor(psum, 32);
        lrun += psum;

        // P redistribution via permlane32_swap -> B-frag words
        uint4 F[2][2];
        #pragma unroll
        for (int ks = 0; ks < 2; ++ks) {
            unsigned a0 = u[ks][0], b0 = u[ks][2];
            unsigned a1 = u[ks][1], b1 = u[ks][3];
            asm("v_permlane32_swap_b32 %0, %1" : "+v"(a0), "+v"(b0));
            asm("v_permlane32_swap_b32 %0, %1" : "+v"(a1), "+v"(b1));
            F[ks][0] = make_uint4(a0, a1, b0, b1);
            unsigned a2 = u[ks][4], b2 = u[ks][6];
            unsigned a3 = u[ks][5], b3 = u[ks][7];
            asm("v_permlane32_swap_b32 %0, %1" : "+v"(a2), "+v"(b2));
            asm("v_permlane32_swap_b32 %0, %1" : "+v"(a3), "+v"(b3));
            F[ks][1] = make_uint4(a2, a3, b2, b3);
        }

        // PV: O^T[d][q] += V^T[d][k] * P^T[k][q]
        #pragma unroll
        for (int t = 0; t < 2; ++t)
            #pragma unroll
            for (int ks = 0; ks < 2; ++ks)
                #pragma unroll
                for (int kc = 0; kc < 2; ++kc)
                    OT[t] = __builtin_amdgcn_mfma_f32_32x32x16_bf16(
                        vf[t][ks][kc], __builtin_bit_cast(bf16x8, F[ks][kc]), OT[t], 0, 0, 0);

        Mcur = Mnext;
    }

    // ---- merge the two K-halves (lane-local per q) ----
    if (khalf) {
        #pragma unroll
        for (int t = 0; t < 2; ++t)
            #pragma unroll
            for (int c = 0; c < 4; ++c)
                Osh[qhalf][t * 4 + c][l] = (f32x4){OT[t][4 * c], OT[t][4 * c + 1],
                                                   OT[t][4 * c + 2], OT[t][4 * c + 3]};
        mlsh[qhalf][0][l] = mrun;
        mlsh[qhalf][1][l] = lrun;
    }
    __syncthreads();
    if (khalf) return;

    const float mb2 = mlsh[qhalf][0][l];
    const float lb2 = mlsh[qhalf][1][l];
    const float mm = fmaxf(mrun, mb2);
    const float sa = exp2f(mrun - mm);
    const float sb = exp2f(mb2 - mm);
    const float linv = 1.0f / (lrun * sa + lb2 * sb);

    __bf16* oh = attn_h + (size_t)(b * S + q0 + lq) * DIMM + gh * HD;
    __bf16* ol = attn_l + (size_t)(b * S + q0 + lq) * DIMM + gh * HD;
    #pragma unroll
    for (int t = 0; t < 2; ++t)
        #pragma unroll
        for (int j = 0; j < 4; ++j) {
            const f32x4 ob = Osh[qhalf][t * 4 + j][l];
            const int d0 = 32 * t + 8 * j + 4 * h;
            unsigned short hv[4], lv[4];
            #pragma unroll
            for (int c = 0; c < 4; ++c) {
                const float v = (OT[t][4 * j + c] * sa + ob[c] * sb) * linv;
                const __bf16 hb = (__bf16)v;
                hv[c] = __builtin_bit_cast(unsigned short, hb);
                lv[c] = __builtin_bit_cast(unsigned short, (__bf16)(v - (float)hb));
            }
            *(ushort4*)(oh + d0) = make_ushort4(hv[0], hv[1], hv[2], hv[3]);
            *(ushort4*)(ol + d0) = make_ushort4(lv[0], lv[1], lv[2], lv[3]);
        }
}

extern "C" void kernel_launch(void* const* d_in, const int* in_sizes, int n_in,
                              void* d_out, int out_size, void* d_ws, size_t ws_size,
                              hipStream_t stream) {
    const float* x     = (const float*)d_in[0];
    const float* kv    = (const float*)d_in[1];
    const float* q_w   = (const float*)d_in[2];
    const float* q_b   = (const float*)d_in[3];
    const float* k_w   = (const float*)d_in[4];
    const float* k_b   = (const float*)d_in[5];
    const float* v_w   = (const float*)d_in[6];
    const float* v_b   = (const float*)d_in[7];
    const float* o_w   = (const float*)d_in[8];
    const float* o_b   = (const float*)d_in[9];
    const float* qn_g  = (const float*)d_in[10];
    const float* qn_b  = (const float*)d_in[11];
    const float* kn_g  = (const float*)d_in[12];
    const float* kn_b  = (const float*)d_in[13];
    const float* vemb  = (const float*)d_in[14];
    const int*   qvar  = (const int*)d_in[15];
    const int*   kvar  = (const int*)d_in[16];
    const int*   qtime = (const int*)d_in[17];
    const int*   ktime = (const int*)d_in[18];
    float* out = (float*)d_out;
    char*  W   = (char*)d_ws;

    const size_t MB = 1u << 20;
    __bf16* xh     = (__bf16*)(W);                 // 0-8   -> attn_h
    __bf16* kvh    = (__bf16*)(W + 8 * MB);        // 8-16  -> attn_l
    __bf16* q_lin  = (__bf16*)(W + 16 * MB);       // 16-24 (dead after q_transform)
    __bf16* kv_lin = (__bf16*)(W + 24 * MB);       // 24-28 (dead after k_t/v_frag)
    unsigned long long* vmask = (unsigned long long*)(W + 16 * MB);  // reuse q_lin, 512KB
    __bf16* q_nb   = (__bf16*)(W + 28 * MB);       // 28-36 (overlays qwh/kvwh/kvb)
    __bf16* qwh    = (__bf16*)(W + 28 * MB);
    __bf16* kvwh   = (__bf16*)(W + 30 * MB);
    float*  kvb    = (float*)(W + 31 * MB);
    __bf16* kfrag  = (__bf16*)(W + 36 * MB);       // 36-38 (frag-major K)
    __bf16* vfrag  = (__bf16*)(W + 38 * MB);       // 38-40 (frag-major V)
    __bf16* owh    = (__bf16*)(W + 40 * MB);       // 40-42
    __bf16* owl    = (__bf16*)(W + 42 * MB);       // 42-44
    __bf16* attn_h = xh;
    __bf16* attn_l = kvh;

    dim3 blk(256);

    cvt_all<<<5377, blk, 0, stream>>>(x, kv, q_w, k_w, v_w, o_w, k_b, v_b,
                                      xh, kvh, qwh, kvwh, owh, owl, kvb);

    gemm_mfma<64, false, true><<<dim3(16, 32), blk, 0, stream>>>(
        xh, nullptr, qwh, nullptr, q_b, (void*)q_lin, 1024, 1024);
    gemm_mfma<64, false, true><<<dim3(8, 32), blk, 0, stream>>>(
        kvh, nullptr, kvwh, nullptr, kvb, (void*)kv_lin, 512, 1024);

    q_transform<<<(4 * G * HPG * S) / 4, blk, 0, stream>>>(q_lin, qn_g, qn_b, qtime, q_nb);
    k_transform<<<(4 * G * S) / 4,       blk, 0, stream>>>(kv_lin, kn_g, kn_b, ktime, kfrag);
    v_frag_k<<<16 * 16,                  blk, 0, stream>>>(kv_lin, vfrag);

    var_mask<<<1024, blk, 0, stream>>>(qvar, kvar, vmask);   // q_lin dead by now

    flash_mfma<<<64 * 16, blk, 0, stream>>>(
        q_nb, kfrag, vfrag, vemb, vmask, attn_h, attn_l);

    gemm_mfma<64, true, false><<<dim3(16, 32), blk, 0, stream>>>(
        attn_h, attn_l, owh, owl, o_b, (void*)out, 1024, 1024);
}

// Round 8
// 162.988 us; speedup vs baseline: 1.5386x; 1.0033x over previous
//
#include <hip/hip_runtime.h>
#include <math.h>

#define S 1024
#define DIMM 1024
#define G 4
#define HPG 4
#define HD 64
#define PW 32
#define SCALE 0.125f
#define LNEPS 1e-5f

typedef __bf16 bf16x8 __attribute__((ext_vector_type(8)));
typedef float  f32x4  __attribute__((ext_vector_type(4)));
typedef float  f32x16 __attribute__((ext_vector_type(16)));

// ---------------- fused f32->bf16 conversions + bias concat ----------------
__global__ __launch_bounds__(256)
void cvt_all(const float* __restrict__ x, const float* __restrict__ kv,
             const float* __restrict__ qw, const float* __restrict__ kw,
             const float* __restrict__ vw, const float* __restrict__ ow,
             const float* __restrict__ kb, const float* __restrict__ vb_,
             __bf16* __restrict__ xh, __bf16* __restrict__ kvh,
             __bf16* __restrict__ qwh, __bf16* __restrict__ kvwh,
             __bf16* __restrict__ owh, __bf16* __restrict__ owl,
             float* __restrict__ kvbias) {
    if (blockIdx.x == 5376) {
        kvbias[threadIdx.x]       = kb[threadIdx.x];
        kvbias[256 + threadIdx.x] = vb_[threadIdx.x];
        return;
    }
    long j = (long)blockIdx.x * 256 + threadIdx.x;
    const float* src; __bf16* dh; __bf16* dl = nullptr;
    if (j < 524288)            { src = x;  dh = xh; }
    else if ((j -= 524288) < 524288) { src = kv; dh = kvh; }
    else if ((j -= 524288) < 131072) { src = qw; dh = qwh; }
    else if ((j -= 131072) < 32768)  { src = kw; dh = kvwh; }
    else if ((j -= 32768) < 32768)   { src = vw; dh = kvwh + 262144; }
    else { j -= 32768; src = ow; dh = owh; dl = owl; }
    const float4 a = *(const float4*)(src + j * 8);
    const float4 b = *(const float4*)(src + j * 8 + 4);
    const float v[8] = {a.x, a.y, a.z, a.w, b.x, b.y, b.z, b.w};
    bf16x8 H;
    #pragma unroll
    for (int e = 0; e < 8; ++e) H[e] = (__bf16)v[e];
    *(bf16x8*)(dh + j * 8) = H;
    if (dl != nullptr) {
        bf16x8 L;
        #pragma unroll
        for (int e = 0; e < 8; ++e) L[e] = (__bf16)(v[e] - (float)H[e]);
        *(bf16x8*)(dl + j * 8) = L;
    }
}

// ---------------- var-id equality masks, transposed: mask[(b*16+kt)*1024+q] ----
__global__ __launch_bounds__(256)
void var_mask(const int* __restrict__ qvar, const int* __restrict__ kvar,
              unsigned long long* __restrict__ mask) {
    const int wid  = blockIdx.x * 4 + (threadIdx.x >> 6);   // b*1024 + q
    const int lane = threadIdx.x & 63;
    const int b = wid >> 10;
    const int q = wid & 1023;
    const int qv = qvar[wid];
    const int* kb = kvar + (b << 10);
    #pragma unroll 4
    for (int t = 0; t < 16; ++t) {
        const unsigned long long bal = __ballot(qv == kb[t * 64 + lane]);
        if (lane == 0) mask[(size_t)(b * 16 + t) * 1024 + q] = bal;
    }
}

// ---------------- bf16 MFMA GEMM (m97 structure) ----------------
__device__ __forceinline__ void gld_lds16(const __bf16* g, __bf16* lds) {
    __builtin_amdgcn_global_load_lds(
        (const __attribute__((address_space(1))) void*)g,
        (__attribute__((address_space(3))) void*)lds, 16, 0, 0);
}

template<int NB, bool SPLIT, bool OUTBF>
__global__ __launch_bounds__(256)
void gemm_mfma(const __bf16* __restrict__ Ah, const __bf16* __restrict__ Al,
               const __bf16* __restrict__ Wh, const __bf16* __restrict__ Wl,
               const float* __restrict__ bias, void* __restrict__ Cout,
               const int N, const int K) {
    constexpr int WN  = NB / 2;
    constexpr int FN  = WN / 16;
    constexpr int NWC = NB / 16;
    __shared__ __bf16 Ahs[128][32];
    __shared__ __bf16 Whs[NB][32];
    __shared__ __bf16 Als[SPLIT ? 128 : 1][32];
    __shared__ __bf16 Wls[SPLIT ? NB : 1][32];

    const int tid = threadIdx.x;
    const int w = tid >> 6, l = tid & 63;
    const int lr = l & 15, lh = l >> 4;
    const int wr = w >> 1, wc = w & 1;
    const int m0 = blockIdx.y * 128, n0 = blockIdx.x * NB;
    const int srow = l >> 2, scol = (l & 3) * 8;

    f32x4 acc[4][FN];
    #pragma unroll
    for (int i = 0; i < 4; ++i)
        #pragma unroll
        for (int j = 0; j < FN; ++j) acc[i][j] = (f32x4){0.f, 0.f, 0.f, 0.f};

    const __bf16* Abp = Ah + (size_t)(m0 + srow) * K + scol;
    const __bf16* Wbp = Wh + (size_t)(n0 + srow) * K + scol;
    const __bf16* Alp = SPLIT ? (Al + (size_t)(m0 + srow) * K + scol) : nullptr;
    const __bf16* Wlp = SPLIT ? (Wl + (size_t)(n0 + srow) * K + scol) : nullptr;

    for (int k0 = 0; k0 < K; k0 += 32) {
        #pragma unroll
        for (int c = 0; c < 2; ++c) {
            const int ch = c * 4 + w;
            gld_lds16(Abp + (size_t)ch * 16 * K + k0, &Ahs[ch * 16][0]);
            if constexpr (SPLIT)
                gld_lds16(Alp + (size_t)ch * 16 * K + k0, &Als[ch * 16][0]);
        }
        #pragma unroll
        for (int c = 0; c < NWC / 4; ++c) {
            const int ch = c * 4 + w;
            gld_lds16(Wbp + (size_t)ch * 16 * K + k0, &Whs[ch * 16][0]);
            if constexpr (SPLIT)
                gld_lds16(Wlp + (size_t)ch * 16 * K + k0, &Wls[ch * 16][0]);
        }
        __syncthreads();

        bf16x8 af[4], bfr[FN];
        #pragma unroll
        for (int i = 0; i < 4; ++i) af[i] = *(const bf16x8*)&Ahs[wr * 64 + 16 * i + lr][lh * 8];
        #pragma unroll
        for (int j = 0; j < FN; ++j) bfr[j] = *(const bf16x8*)&Whs[wc * WN + 16 * j + lr][lh * 8];
        #pragma unroll
        for (int i = 0; i < 4; ++i)
            #pragma unroll
            for (int j = 0; j < FN; ++j)
                acc[i][j] = __builtin_amdgcn_mfma_f32_16x16x32_bf16(af[i], bfr[j], acc[i][j], 0, 0, 0);
        if constexpr (SPLIT) {
            bf16x8 al8[4], wl8[FN];
            #pragma unroll
            for (int i = 0; i < 4; ++i) al8[i] = *(const bf16x8*)&Als[wr * 64 + 16 * i + lr][lh * 8];
            #pragma unroll
            for (int j = 0; j < FN; ++j) wl8[j] = *(const bf16x8*)&Wls[wc * WN + 16 * j + lr][lh * 8];
            #pragma unroll
            for (int i = 0; i < 4; ++i)
                #pragma unroll
                for (int j = 0; j < FN; ++j) {
                    acc[i][j] = __builtin_amdgcn_mfma_f32_16x16x32_bf16(al8[i], bfr[j], acc[i][j], 0, 0, 0);
                    acc[i][j] = __builtin_amdgcn_mfma_f32_16x16x32_bf16(af[i], wl8[j], acc[i][j], 0, 0, 0);
                }
        }
        __syncthreads();
    }

    float bv[FN];
    #pragma unroll
    for (int j = 0; j < FN; ++j) bv[j] = bias[n0 + wc * WN + 16 * j + lr];
    #pragma unroll
    for (int i = 0; i < 4; ++i) {
        const int mb = m0 + wr * 64 + 16 * i + 4 * lh;
        #pragma unroll
        for (int j = 0; j < FN; ++j) {
            const int n = n0 + wc * WN + 16 * j + lr;
            #pragma unroll
            for (int r = 0; r < 4; ++r) {
                const float v = acc[i][j][r] + bv[j];
                if constexpr (OUTBF) ((__bf16*)Cout)[(size_t)(mb + r) * N + n] = (__bf16)v;
                else                 ((float*)Cout)[(size_t)(mb + r) * N + n] = v;
            }
        }
    }
}

// ---------------- wave helpers ----------------
__device__ inline float wave64_sum(float v) {
    #pragma unroll
    for (int off = 32; off >= 1; off >>= 1) v += __shfl_xor(v, off);
    return v;
}

// ---------------- q: LayerNorm + rotary -> bf16 [bgh][s][d] ----------------
__global__ __launch_bounds__(256)
void q_transform(const __bf16* __restrict__ q_lin, const float* __restrict__ gam,
                 const float* __restrict__ bet, const int* __restrict__ t_id,
                 __bf16* __restrict__ q_n) {
    const int row  = blockIdx.x * 4 + (threadIdx.x >> 6);
    const int lane = threadIdx.x & 63;
    const int s    = row & (S - 1);
    const int bgh  = row >> 10;
    const int b    = bgh >> 4;
    const int gh   = bgh & 15;
    float x = (float)q_lin[(size_t)(b * S + s) * DIMM + gh * HD + lane];
    const float m = wave64_sum(x) * (1.0f / 64.0f);
    const float d = x - m;
    const float v = wave64_sum(d * d) * (1.0f / 64.0f);
    float y = d * rsqrtf(v + LNEPS) * gam[lane] + bet[lane];
    const float partner = __shfl_xor(y, 1);
    if (lane < PW) {
        const int i = lane >> 1;
        const float theta = expf(-0.57564627324851f * (float)i);
        const float ang = (float)t_id[b * S + s] * theta;
        const float cs = cosf(ang), sn = sinf(ang);
        y = cs * y + sn * ((lane & 1) ? partner : -partner);
    }
    q_n[(size_t)row * HD + lane] = (__bf16)y;
}

// ---------------- k: LayerNorm + rotary -> bf16 FRAGMENT-MAJOR layout --------
__global__ __launch_bounds__(256)
void k_transform(const __bf16* __restrict__ kv_lin, const float* __restrict__ gam,
                 const float* __restrict__ bet, const int* __restrict__ t_id,
                 __bf16* __restrict__ kfrag) {
    const int row  = blockIdx.x * 4 + (threadIdx.x >> 6);
    const int lane = threadIdx.x & 63;
    const int s    = row & (S - 1);
    const int bg   = row >> 10;
    const int b    = bg >> 2;
    const int g    = bg & 3;
    float x = (float)kv_lin[(size_t)(b * S + s) * 512 + g * HD + lane];
    const float m = wave64_sum(x) * (1.0f / 64.0f);
    const float d = x - m;
    const float v = wave64_sum(d * d) * (1.0f / 64.0f);
    float y = d * rsqrtf(v + LNEPS) * gam[lane] + bet[lane];
    const float partner = __shfl_xor(y, 1);
    if (lane < PW) {
        const int i = lane >> 1;
        const float theta = expf(-0.57564627324851f * (float)i);
        const float ang = (float)t_id[b * S + s] * theta;
        const float cs = cosf(ang), sn = sinf(ang);
        y = cs * y + sn * ((lane & 1) ? partner : -partner);
    }
    const size_t idx = (size_t)(((bg * 16 + (s >> 6)) * 8 + ((s >> 5) & 1) * 4
                                 + (lane >> 4)) * 512)
                     + ((lane >> 3) & 1) * 256 + (s & 31) * 8 + (lane & 7);
    kfrag[idx] = (__bf16)y;
}

// ---------------- V -> fragment-major ----------------
__global__ __launch_bounds__(256)
void v_frag_k(const __bf16* __restrict__ kv_lin, __bf16* __restrict__ vfrag) {
    __shared__ float T[64][65];   // T[k_local][d]
    const int bg = blockIdx.x >> 4;
    const int kt = blockIdx.x & 15;
    const int b = bg >> 2, g = bg & 3;
    const int tx = threadIdx.x & 63, ty = threadIdx.x >> 6;
    const __bf16* src = kv_lin + ((size_t)(b * S) + kt * 64) * 512 + 256 + g * HD;
    #pragma unroll
    for (int i = 0; i < 16; ++i) {
        const int kl = ty + 4 * i;
        T[kl][tx] = (float)src[(size_t)kl * 512 + tx];
    }
    __syncthreads();
    __bf16* dst = vfrag + (size_t)bg * 65536 + (size_t)kt * 4096;
    #pragma unroll
    for (int half = 0; half < 2; ++half) {
        const int c  = half * 256 + threadIdx.x;
        const int lq = c & 31;
        const int h  = (c >> 5) & 1;
        const int kc = (c >> 6) & 1;
        const int ks = (c >> 7) & 1;
        const int t  = (c >> 8) & 1;
        const int kl = 32 * ks + 16 * kc + 8 * h;
        const int d  = 32 * t + lq;
        bf16x8 o;
        #pragma unroll
        for (int e = 0; e < 8; ++e) o[e] = (__bf16)T[kl + e][d];
        *(bf16x8*)(dst + ((size_t)((t * 2 + ks) * 2 + kc) * 2 + h) * 256 + lq * 8) = o;
    }
}

// ---------------- flash attention v6: static-ref softmax, K-split x4 ----------
// block = 4 waves = 1 q-group (32 rows) x 4 K-quarters (4 tiles each).
// Softmax uses fixed reference 12.5 (scores bounded by Cauchy-Schwarz: 11.8),
// so no running max, no rescale, no per-tile shuffles; merge = pure sums.
__global__ __launch_bounds__(256, 2)
void flash_mfma(const __bf16* __restrict__ q_n, const __bf16* __restrict__ kfrag,
                const __bf16* __restrict__ vfrag, const float* __restrict__ var_emb,
                const unsigned long long* __restrict__ vmask,
                __bf16* __restrict__ attn_h, __bf16* __restrict__ attn_l) {
    __shared__ f32x4 Osh[2][8][64];
    __shared__ float lsh[2][64];

    const int tid = threadIdx.x;
    const int w = tid >> 6, l = tid & 63;
    const int lq = l & 31;
    const int h  = l >> 5;
    const int qb  = blockIdx.x & 31;          // q-group (32 rows)
    const int bgh = blockIdx.x >> 5;
    const int b = bgh >> 4, gh = bgh & 15;
    const int bg = bgh >> 2;
    const int q0 = qb * 32;
    const int ktbeg = w * 4;                  // this wave's 4 k-tiles

    // Q B-frags: lane holds Q[q=lq][d = 16*dc + 8*h + e]
    const __bf16* qbase = q_n + ((size_t)bgh * S + q0 + lq) * HD + 8 * h;
    bf16x8 qf[4];
    #pragma unroll
    for (int dc = 0; dc < 4; ++dc) qf[dc] = *(const bf16x8*)(qbase + 16 * dc);

    constexpr float L2E = 1.4426950408889634f;
    const float w0l12 = var_emb[gh] * L2E - 12.5f;           // bias - static ref
    const float dwl   = (var_emb[16 + gh] - var_emb[gh]) * L2E;
    const float sc2   = SCALE * L2E;

    const __bf16* kfr = kfrag + (size_t)bg * 65536 + (size_t)l * 8;
    const __bf16* vfr = vfrag + (size_t)bg * 65536 + (size_t)l * 8;
    const unsigned long long* mbase = vmask + (size_t)(b << 14) + q0 + lq;

    f32x16 OT[2];
    #pragma unroll
    for (int t = 0; t < 2; ++t)
        #pragma unroll
        for (int r = 0; r < 16; ++r) OT[t][r] = 0.0f;
    float lrun = 0.0f;

    // preload K tile ktbeg + its mask
    bf16x8 kf[2][4];
    #pragma unroll
    for (int ks = 0; ks < 2; ++ks)
        #pragma unroll
        for (int dc = 0; dc < 4; ++dc)
            kf[ks][dc] = *(const bf16x8*)(kfr + (size_t)(ktbeg * 8 + ks * 4 + dc) * 512);
    unsigned long long Mcur = mbase[(size_t)ktbeg << 10] >> (4 * h);

    for (int kt = ktbeg; kt < ktbeg + 4; ++kt) {
        // V A-frags for current tile
        bf16x8 vf[2][2][2];
        #pragma unroll
        for (int t = 0; t < 2; ++t)
            #pragma unroll
            for (int ks = 0; ks < 2; ++ks)
                #pragma unroll
                for (int kc = 0; kc < 2; ++kc)
                    vf[t][ks][kc] = *(const bf16x8*)
                        (vfr + (size_t)(((kt * 2 + t) * 2 + ks) * 2 + kc) * 512);

        // swapped QK^T: lane gets S[k = 64kt + 32ks + (r&3)+8(r>>2)+4h][q=lq]
        f32x16 st[2];
        __builtin_amdgcn_s_setprio(1);
        #pragma unroll
        for (int ks = 0; ks < 2; ++ks) {
            f32x16 acc;
            #pragma unroll
            for (int r = 0; r < 16; ++r) acc[r] = 0.0f;
            #pragma unroll
            for (int dc = 0; dc < 4; ++dc)
                acc = __builtin_amdgcn_mfma_f32_32x32x16_bf16(kf[ks][dc], qf[dc], acc, 0, 0, 0);
            st[ks] = acc;
        }
        __builtin_amdgcn_s_setprio(0);

        // prefetch next K tile + mask
        const int kn = (kt + 1 < ktbeg + 4) ? kt + 1 : ktbeg;
        #pragma unroll
        for (int ks = 0; ks < 2; ++ks)
            #pragma unroll
            for (int dc = 0; dc < 4; ++dc)
                kf[ks][dc] = *(const bf16x8*)(kfr + (size_t)(kn * 8 + ks * 4 + dc) * 512);
        const unsigned long long Mnext = mbase[(size_t)kn << 10] >> (4 * h);

        // P = exp2(st*sc2 + bias - 12.5); no max, no branch, no shuffles
        const unsigned mlo = (unsigned)Mcur;
        const unsigned mhi = (unsigned)(Mcur >> 32);
        unsigned int u[2][8];
        #pragma unroll
        for (int ks = 0; ks < 2; ++ks) {
            const unsigned wm = ks ? mhi : mlo;
            #pragma unroll
            for (int jj = 0; jj < 8; ++jj) {
                const int r0 = 2 * jj, r1 = 2 * jj + 1;
                const int jr0 = (r0 & 3) + 8 * (r0 >> 2);
                const int jr1 = (r1 & 3) + 8 * (r1 >> 2);
                const float b0 = fmaf((float)((wm >> jr0) & 1u), dwl, w0l12);
                const float b1 = fmaf((float)((wm >> jr1) & 1u), dwl, w0l12);
                const float p0 = exp2f(fmaf(st[ks][r0], sc2, b0));
                const float p1 = exp2f(fmaf(st[ks][r1], sc2, b1));
                lrun += p0 + p1;
                asm("v_cvt_pk_bf16_f32 %0, %1, %2" : "=v"(u[ks][jj]) : "v"(p0), "v"(p1));
            }
        }

        // P redistribution via permlane32_swap -> B-frag words
        uint4 F[2][2];
        #pragma unroll
        for (int ks = 0; ks < 2; ++ks) {
            unsigned a0 = u[ks][0], b0 = u[ks][2];
            unsigned a1 = u[ks][1], b1 = u[ks][3];
            asm("v_permlane32_swap_b32 %0, %1" : "+v"(a0), "+v"(b0));
            asm("v_permlane32_swap_b32 %0, %1" : "+v"(a1), "+v"(b1));
            F[ks][0] = make_uint4(a0, a1, b0, b1);
            unsigned a2 = u[ks][4], b2 = u[ks][6];
            unsigned a3 = u[ks][5], b3 = u[ks][7];
            asm("v_permlane32_swap_b32 %0, %1" : "+v"(a2), "+v"(b2));
            asm("v_permlane32_swap_b32 %0, %1" : "+v"(a3), "+v"(b3));
            F[ks][1] = make_uint4(a2, a3, b2, b3);
        }

        // PV: O^T[d][q] += V^T[d][k] * P^T[k][q]
        __builtin_amdgcn_s_setprio(1);
        #pragma unroll
        for (int t = 0; t < 2; ++t)
            #pragma unroll
            for (int ks = 0; ks < 2; ++ks)
                #pragma unroll
                for (int kc = 0; kc < 2; ++kc)
                    OT[t] = __builtin_amdgcn_mfma_f32_32x32x16_bf16(
                        vf[t][ks][kc], __builtin_bit_cast(bf16x8, F[ks][kc]), OT[t], 0, 0, 0);
        __builtin_amdgcn_s_setprio(0);

        Mcur = Mnext;
    }

    // ---- merge 4 K-quarters: pure sums (softmax ref is global) ----
    if (w & 1) {
        #pragma unroll
        for (int t = 0; t < 2; ++t)
            #pragma unroll
            for (int c = 0; c < 4; ++c)
                Osh[w >> 1][t * 4 + c][l] = (f32x4){OT[t][4 * c], OT[t][4 * c + 1],
                                                    OT[t][4 * c + 2], OT[t][4 * c + 3]};
        lsh[w >> 1][l] = lrun;
    }
    __syncthreads();
    if (!(w & 1)) {
        #pragma unroll
        for (int t = 0; t < 2; ++t)
            #pragma unroll
            for (int c = 0; c < 4; ++c) {
                const f32x4 o = Osh[w >> 1][t * 4 + c][l];
                OT[t][4 * c]     += o[0];
                OT[t][4 * c + 1] += o[1];
                OT[t][4 * c + 2] += o[2];
                OT[t][4 * c + 3] += o[3];
            }
        lrun += lsh[w >> 1][l];
    }
    __syncthreads();
    if (w == 2) {
        #pragma unroll
        for (int t = 0; t < 2; ++t)
            #pragma unroll
            for (int c = 0; c < 4; ++c)
                Osh[0][t * 4 + c][l] = (f32x4){OT[t][4 * c], OT[t][4 * c + 1],
                                               OT[t][4 * c + 2], OT[t][4 * c + 3]};
        lsh[0][l] = lrun;
    }
    __syncthreads();
    if (w != 0) return;

    #pragma unroll
    for (int t = 0; t < 2; ++t)
        #pragma unroll
        for (int c = 0; c < 4; ++c) {
            const f32x4 o = Osh[0][t * 4 + c][l];
            OT[t][4 * c]     += o[0];
            OT[t][4 * c + 1] += o[1];
            OT[t][4 * c + 2] += o[2];
            OT[t][4 * c + 3] += o[3];
        }
    lrun += lsh[0][l];
    lrun += __shfl_xor(lrun, 32);   // combine lane halves (same q, disjoint k)
    const float linv = 1.0f / lrun;

    __bf16* oh = attn_h + (size_t)(b * S + q0 + lq) * DIMM + gh * HD;
    __bf16* ol = attn_l + (size_t)(b * S + q0 + lq) * DIMM + gh * HD;
    #pragma unroll
    for (int t = 0; t < 2; ++t)
        #pragma unroll
        for (int j = 0; j < 4; ++j) {
            const int d0 = 32 * t + 8 * j + 4 * h;
            unsigned short hv[4], lv[4];
            #pragma unroll
            for (int c = 0; c < 4; ++c) {
                const float v = OT[t][4 * j + c] * linv;
                const __bf16 hb = (__bf16)v;
                hv[c] = __builtin_bit_cast(unsigned short, hb);
                lv[c] = __builtin_bit_cast(unsigned short, (__bf16)(v - (float)hb));
            }
            *(ushort4*)(oh + d0) = make_ushort4(hv[0], hv[1], hv[2], hv[3]);
            *(ushort4*)(ol + d0) = make_ushort4(lv[0], lv[1], lv[2], lv[3]);
        }
}

extern "C" void kernel_launch(void* const* d_in, const int* in_sizes, int n_in,
                              void* d_out, int out_size, void* d_ws, size_t ws_size,
                              hipStream_t stream) {
    const float* x     = (const float*)d_in[0];
    const float* kv    = (const float*)d_in[1];
    const float* q_w   = (const float*)d_in[2];
    const float* q_b   = (const float*)d_in[3];
    const float* k_w   = (const float*)d_in[4];
    const float* k_b   = (const float*)d_in[5];
    const float* v_w   = (const float*)d_in[6];
    const float* v_b   = (const float*)d_in[7];
    const float* o_w   = (const float*)d_in[8];
    const float* o_b   = (const float*)d_in[9];
    const float* qn_g  = (const float*)d_in[10];
    const float* qn_b  = (const float*)d_in[11];
    const float* kn_g  = (const float*)d_in[12];
    const float* kn_b  = (const float*)d_in[13];
    const float* vemb  = (const float*)d_in[14];
    const int*   qvar  = (const int*)d_in[15];
    const int*   kvar  = (const int*)d_in[16];
    const int*   qtime = (const int*)d_in[17];
    const int*   ktime = (const int*)d_in[18];
    float* out = (float*)d_out;
    char*  W   = (char*)d_ws;

    const size_t MB = 1u << 20;
    __bf16* xh     = (__bf16*)(W);                 // 0-8   -> attn_h
    __bf16* kvh    = (__bf16*)(W + 8 * MB);        // 8-16  -> attn_l
    __bf16* q_lin  = (__bf16*)(W + 16 * MB);       // 16-24 (dead after q_transform)
    __bf16* kv_lin = (__bf16*)(W + 24 * MB);       // 24-28 (dead after k_t/v_frag)
    unsigned long long* vmask = (unsigned long long*)(W + 16 * MB);  // reuse q_lin
    __bf16* q_nb   = (__bf16*)(W + 28 * MB);       // 28-36 (overlays qwh/kvwh/kvb)
    __bf16* qwh    = (__bf16*)(W + 28 * MB);
    __bf16* kvwh   = (__bf16*)(W + 30 * MB);
    float*  kvb    = (float*)(W + 31 * MB);
    __bf16* kfrag  = (__bf16*)(W + 36 * MB);       // 36-38 (frag-major K)
    __bf16* vfrag  = (__bf16*)(W + 38 * MB);       // 38-40 (frag-major V)
    __bf16* owh    = (__bf16*)(W + 40 * MB);       // 40-42
    __bf16* owl    = (__bf16*)(W + 42 * MB);       // 42-44
    __bf16* attn_h = xh;
    __bf16* attn_l = kvh;

    dim3 blk(256);

    cvt_all<<<5377, blk, 0, stream>>>(x, kv, q_w, k_w, v_w, o_w, k_b, v_b,
                                      xh, kvh, qwh, kvwh, owh, owl, kvb);

    gemm_mfma<64, false, true><<<dim3(16, 32), blk, 0, stream>>>(
        xh, nullptr, qwh, nullptr, q_b, (void*)q_lin, 1024, 1024);
    gemm_mfma<64, false, true><<<dim3(8, 32), blk, 0, stream>>>(
        kvh, nullptr, kvwh, nullptr, kvb, (void*)kv_lin, 512, 1024);

    q_transform<<<(4 * G * HPG * S) / 4, blk, 0, stream>>>(q_lin, qn_g, qn_b, qtime, q_nb);
    k_transform<<<(4 * G * S) / 4,       blk, 0, stream>>>(kv_lin, kn_g, kn_b, ktime, kfrag);
    v_frag_k<<<16 * 16,                  blk, 0, stream>>>(kv_lin, vfrag);

    var_mask<<<1024, blk, 0, stream>>>(qvar, kvar, vmask);   // q_lin dead by now

    flash_mfma<<<64 * 32, blk, 0, stream>>>(
        q_nb, kfrag, vfrag, vemb, vmask, attn_h, attn_l);

    gemm_mfma<64, true, false><<<dim3(16, 32), blk, 0, stream>>>(
        attn_h, attn_l, owh, owl, o_b, (void*)out, 1024, 1024);
}

// Round 9
// 131.034 us; speedup vs baseline: 1.9138x; 1.2439x over previous
//
#include <hip/hip_runtime.h>
#include <math.h>

#define S 1024
#define DIMM 1024
#define G 4
#define HPG 4
#define HD 64
#define PW 32
#define SCALE 0.125f
#define LNEPS 1e-5f

typedef __bf16 bf16x8 __attribute__((ext_vector_type(8)));
typedef float  f32x4  __attribute__((ext_vector_type(4)));
typedef float  f32x16 __attribute__((ext_vector_type(16)));

// ---------------- fused f32->bf16 conversions + bias concat ----------------
__global__ __launch_bounds__(256)
void cvt_all(const float* __restrict__ x, const float* __restrict__ kv,
             const float* __restrict__ qw, const float* __restrict__ kw,
             const float* __restrict__ vw, const float* __restrict__ ow,
             const float* __restrict__ kb, const float* __restrict__ vb_,
             __bf16* __restrict__ xh, __bf16* __restrict__ kvh,
             __bf16* __restrict__ qwh, __bf16* __restrict__ kvwh,
             __bf16* __restrict__ owh, __bf16* __restrict__ owl,
             float* __restrict__ kvbias) {
    if (blockIdx.x == 5376) {
        kvbias[threadIdx.x]       = kb[threadIdx.x];
        kvbias[256 + threadIdx.x] = vb_[threadIdx.x];
        return;
    }
    long j = (long)blockIdx.x * 256 + threadIdx.x;
    const float* src; __bf16* dh; __bf16* dl = nullptr;
    if (j < 524288)            { src = x;  dh = xh; }
    else if ((j -= 524288) < 524288) { src = kv; dh = kvh; }
    else if ((j -= 524288) < 131072) { src = qw; dh = qwh; }
    else if ((j -= 131072) < 32768)  { src = kw; dh = kvwh; }
    else if ((j -= 32768) < 32768)   { src = vw; dh = kvwh + 262144; }
    else { j -= 32768; src = ow; dh = owh; dl = owl; }
    const float4 a = *(const float4*)(src + j * 8);
    const float4 b = *(const float4*)(src + j * 8 + 4);
    const float v[8] = {a.x, a.y, a.z, a.w, b.x, b.y, b.z, b.w};
    bf16x8 H;
    #pragma unroll
    for (int e = 0; e < 8; ++e) H[e] = (__bf16)v[e];
    *(bf16x8*)(dh + j * 8) = H;
    if (dl != nullptr) {
        bf16x8 L;
        #pragma unroll
        for (int e = 0; e < 8; ++e) L[e] = (__bf16)(v[e] - (float)H[e]);
        *(bf16x8*)(dl + j * 8) = L;
    }
}

// ---------------- bf16 MFMA GEMM helpers ----------------
__device__ __forceinline__ void gld_lds16(const __bf16* g, __bf16* lds) {
    __builtin_amdgcn_global_load_lds(
        (const __attribute__((address_space(1))) void*)g,
        (__attribute__((address_space(3))) void*)lds, 16, 0, 0);
}

// ---------------- fused q+kv projections (both NB=64, K=1024) ----------------
__global__ __launch_bounds__(256)
void gemm_qkv(const __bf16* __restrict__ xh,  const __bf16* __restrict__ qwh,
              const float* __restrict__ qb,   __bf16* __restrict__ q_lin,
              const __bf16* __restrict__ kvh, const __bf16* __restrict__ kvwh,
              const float* __restrict__ kvb,  __bf16* __restrict__ kv_lin) {
    constexpr int K = 1024;
    __shared__ __bf16 Ahs[128][32];
    __shared__ __bf16 Whs[64][32];

    int bid = blockIdx.x;
    const __bf16 *A, *Wm; const float* bias; __bf16* C; int N, m0, n0;
    if (bid < 512) { A = xh;  Wm = qwh;  bias = qb;  C = q_lin;  N = 1024;
                     m0 = (bid >> 4) * 128; n0 = (bid & 15) * 64; }
    else { bid -= 512; A = kvh; Wm = kvwh; bias = kvb; C = kv_lin; N = 512;
           m0 = (bid >> 3) * 128; n0 = (bid & 7) * 64; }

    const int tid = threadIdx.x;
    const int w = tid >> 6, l = tid & 63;
    const int lr = l & 15, lh = l >> 4;
    const int wr = w >> 1, wc = w & 1;
    const int srow = l >> 2, scol = (l & 3) * 8;

    f32x4 acc[4][2];
    #pragma unroll
    for (int i = 0; i < 4; ++i)
        #pragma unroll
        for (int j = 0; j < 2; ++j) acc[i][j] = (f32x4){0.f, 0.f, 0.f, 0.f};

    const __bf16* Abp = A  + (size_t)(m0 + srow) * K + scol;
    const __bf16* Wbp = Wm + (size_t)(n0 + srow) * K + scol;

    for (int k0 = 0; k0 < K; k0 += 32) {
        #pragma unroll
        for (int c = 0; c < 2; ++c)
            gld_lds16(Abp + (size_t)(c * 4 + w) * 16 * K + k0, &Ahs[(c * 4 + w) * 16][0]);
        gld_lds16(Wbp + (size_t)w * 16 * K + k0, &Whs[w * 16][0]);
        __syncthreads();

        bf16x8 af[4], bfr[2];
        #pragma unroll
        for (int i = 0; i < 4; ++i) af[i] = *(const bf16x8*)&Ahs[wr * 64 + 16 * i + lr][lh * 8];
        #pragma unroll
        for (int j = 0; j < 2; ++j) bfr[j] = *(const bf16x8*)&Whs[wc * 32 + 16 * j + lr][lh * 8];
        #pragma unroll
        for (int i = 0; i < 4; ++i)
            #pragma unroll
            for (int j = 0; j < 2; ++j)
                acc[i][j] = __builtin_amdgcn_mfma_f32_16x16x32_bf16(af[i], bfr[j], acc[i][j], 0, 0, 0);
        __syncthreads();
    }

    float bv[2];
    #pragma unroll
    for (int j = 0; j < 2; ++j) bv[j] = bias[n0 + wc * 32 + 16 * j + lr];
    #pragma unroll
    for (int i = 0; i < 4; ++i) {
        const int mb = m0 + wr * 64 + 16 * i + 4 * lh;
        #pragma unroll
        for (int j = 0; j < 2; ++j) {
            const int n = n0 + wc * 32 + 16 * j + lr;
            #pragma unroll
            for (int r = 0; r < 4; ++r)
                C[(size_t)(mb + r) * N + n] = (__bf16)(acc[i][j][r] + bv[j]);
        }
    }
}

// ---------------- o-projection: 2-term W-split (ah*wh + ah*wl), f32 out ------
__global__ __launch_bounds__(256)
void gemm_o(const __bf16* __restrict__ Ah, const __bf16* __restrict__ Wh,
            const __bf16* __restrict__ Wl, const float* __restrict__ bias,
            float* __restrict__ Cout) {
    constexpr int K = 1024, N = 1024;
    __shared__ __bf16 Ahs[128][32];
    __shared__ __bf16 Whs[64][32];
    __shared__ __bf16 Wls[64][32];

    const int tid = threadIdx.x;
    const int w = tid >> 6, l = tid & 63;
    const int lr = l & 15, lh = l >> 4;
    const int wr = w >> 1, wc = w & 1;
    const int m0 = blockIdx.y * 128, n0 = blockIdx.x * 64;
    const int srow = l >> 2, scol = (l & 3) * 8;

    f32x4 acc[4][2];
    #pragma unroll
    for (int i = 0; i < 4; ++i)
        #pragma unroll
        for (int j = 0; j < 2; ++j) acc[i][j] = (f32x4){0.f, 0.f, 0.f, 0.f};

    const __bf16* Abp = Ah + (size_t)(m0 + srow) * K + scol;
    const __bf16* Whp = Wh + (size_t)(n0 + srow) * K + scol;
    const __bf16* Wlp = Wl + (size_t)(n0 + srow) * K + scol;

    for (int k0 = 0; k0 < K; k0 += 32) {
        #pragma unroll
        for (int c = 0; c < 2; ++c)
            gld_lds16(Abp + (size_t)(c * 4 + w) * 16 * K + k0, &Ahs[(c * 4 + w) * 16][0]);
        gld_lds16(Whp + (size_t)w * 16 * K + k0, &Whs[w * 16][0]);
        gld_lds16(Wlp + (size_t)w * 16 * K + k0, &Wls[w * 16][0]);
        __syncthreads();

        bf16x8 af[4], bh[2], bl[2];
        #pragma unroll
        for (int i = 0; i < 4; ++i) af[i] = *(const bf16x8*)&Ahs[wr * 64 + 16 * i + lr][lh * 8];
        #pragma unroll
        for (int j = 0; j < 2; ++j) {
            bh[j] = *(const bf16x8*)&Whs[wc * 32 + 16 * j + lr][lh * 8];
            bl[j] = *(const bf16x8*)&Wls[wc * 32 + 16 * j + lr][lh * 8];
        }
        #pragma unroll
        for (int i = 0; i < 4; ++i)
            #pragma unroll
            for (int j = 0; j < 2; ++j) {
                acc[i][j] = __builtin_amdgcn_mfma_f32_16x16x32_bf16(af[i], bh[j], acc[i][j], 0, 0, 0);
                acc[i][j] = __builtin_amdgcn_mfma_f32_16x16x32_bf16(af[i], bl[j], acc[i][j], 0, 0, 0);
            }
        __syncthreads();
    }

    float bv[2];
    #pragma unroll
    for (int j = 0; j < 2; ++j) bv[j] = bias[n0 + wc * 32 + 16 * j + lr];
    #pragma unroll
    for (int i = 0; i < 4; ++i) {
        const int mb = m0 + wr * 64 + 16 * i + 4 * lh;
        #pragma unroll
        for (int j = 0; j < 2; ++j) {
            const int n = n0 + wc * 32 + 16 * j + lr;
            #pragma unroll
            for (int r = 0; r < 4; ++r)
                Cout[(size_t)(mb + r) * N + n] = acc[i][j][r] + bv[j];
        }
    }
}

// ---------------- wave helpers ----------------
__device__ inline float wave64_sum(float v) {
    #pragma unroll
    for (int off = 32; off >= 1; off >>= 1) v += __shfl_xor(v, off);
    return v;
}

// ---------------- fused transforms: q_t | k_t | v_frag | var_mask ----------
__global__ __launch_bounds__(256)
void transforms_all(const __bf16* __restrict__ q_lin, const __bf16* __restrict__ kv_lin,
                    const float* __restrict__ qn_g, const float* __restrict__ qn_b,
                    const float* __restrict__ kn_g, const float* __restrict__ kn_b,
                    const int* __restrict__ qtime, const int* __restrict__ ktime,
                    const int* __restrict__ qvar, const int* __restrict__ kvar,
                    __bf16* __restrict__ q_nb, __bf16* __restrict__ kfrag,
                    __bf16* __restrict__ vfrag, unsigned long long* __restrict__ vmask) {
    __shared__ float T[64][65];
    const int bid = blockIdx.x;
    const int lane = threadIdx.x & 63;

    if (bid < 16384) {
        // ---- q: LayerNorm + rotary -> bf16 [bgh][s][d] ----
        const int row = bid * 4 + (threadIdx.x >> 6);
        const int s   = row & (S - 1);
        const int bgh = row >> 10;
        const int b   = bgh >> 4;
        const int gh  = bgh & 15;
        float x = (float)q_lin[(size_t)(b * S + s) * DIMM + gh * HD + lane];
        const float m = wave64_sum(x) * (1.0f / 64.0f);
        const float d = x - m;
        const float v = wave64_sum(d * d) * (1.0f / 64.0f);
        float y = d * rsqrtf(v + LNEPS) * qn_g[lane] + qn_b[lane];
        const float partner = __shfl_xor(y, 1);
        if (lane < PW) {
            const int i = lane >> 1;
            const float theta = expf(-0.57564627324851f * (float)i);
            const float ang = (float)qtime[b * S + s] * theta;
            const float cs = cosf(ang), sn = sinf(ang);
            y = cs * y + sn * ((lane & 1) ? partner : -partner);
        }
        q_nb[(size_t)row * HD + lane] = (__bf16)y;
    } else if (bid < 20480) {
        // ---- k: LayerNorm + rotary -> fragment-major ----
        const int row = (bid - 16384) * 4 + (threadIdx.x >> 6);
        const int s   = row & (S - 1);
        const int bg  = row >> 10;
        const int b   = bg >> 2;
        const int g   = bg & 3;
        float x = (float)kv_lin[(size_t)(b * S + s) * 512 + g * HD + lane];
        const float m = wave64_sum(x) * (1.0f / 64.0f);
        const float d = x - m;
        const float v = wave64_sum(d * d) * (1.0f / 64.0f);
        float y = d * rsqrtf(v + LNEPS) * kn_g[lane] + kn_b[lane];
        const float partner = __shfl_xor(y, 1);
        if (lane < PW) {
            const int i = lane >> 1;
            const float theta = expf(-0.57564627324851f * (float)i);
            const float ang = (float)ktime[b * S + s] * theta;
            const float cs = cosf(ang), sn = sinf(ang);
            y = cs * y + sn * ((lane & 1) ? partner : -partner);
        }
        const size_t idx = (size_t)(((bg * 16 + (s >> 6)) * 8 + ((s >> 5) & 1) * 4
                                     + (lane >> 4)) * 512)
                         + ((lane >> 3) & 1) * 256 + (s & 31) * 8 + (lane & 7);
        kfrag[idx] = (__bf16)y;
    } else if (bid < 20736) {
        // ---- V -> fragment-major ----
        const int vb = bid - 20480;
        const int bg = vb >> 4;
        const int kt = vb & 15;
        const int b = bg >> 2, g = bg & 3;
        const int tx = threadIdx.x & 63, ty = threadIdx.x >> 6;
        const __bf16* src = kv_lin + ((size_t)(b * S) + kt * 64) * 512 + 256 + g * HD;
        #pragma unroll
        for (int i = 0; i < 16; ++i) {
            const int kl = ty + 4 * i;
            T[kl][tx] = (float)src[(size_t)kl * 512 + tx];
        }
        __syncthreads();
        __bf16* dst = vfrag + (size_t)bg * 65536 + (size_t)kt * 4096;
        #pragma unroll
        for (int half = 0; half < 2; ++half) {
            const int c  = half * 256 + threadIdx.x;
            const int lq = c & 31;
            const int h  = (c >> 5) & 1;
            const int kc = (c >> 6) & 1;
            const int ks = (c >> 7) & 1;
            const int t  = (c >> 8) & 1;
            const int kl = 32 * ks + 16 * kc + 8 * h;
            const int d  = 32 * t + lq;
            bf16x8 o;
            #pragma unroll
            for (int e = 0; e < 8; ++e) o[e] = (__bf16)T[kl + e][d];
            *(bf16x8*)(dst + ((size_t)((t * 2 + ks) * 2 + kc) * 2 + h) * 256 + lq * 8) = o;
        }
    } else {
        // ---- var-id equality masks, transposed ----
        const int wid = (bid - 20736) * 4 + (threadIdx.x >> 6);
        const int b = wid >> 10;
        const int q = wid & 1023;
        const int qv = qvar[wid];
        const int* kb = kvar + (b << 10);
        #pragma unroll 4
        for (int t = 0; t < 16; ++t) {
            const unsigned long long bal = __ballot(qv == kb[t * 64 + lane]);
            if (lane == 0) vmask[(size_t)(b * 16 + t) * 1024 + q] = bal;
        }
    }
}

// ---------------- flash attention v7: static-ref softmax, mask preload,
//                  XCD swizzle, hi-only output ----------------
__global__ __launch_bounds__(256, 2)
void flash_mfma(const __bf16* __restrict__ q_n, const __bf16* __restrict__ kfrag,
                const __bf16* __restrict__ vfrag, const float* __restrict__ var_emb,
                const unsigned long long* __restrict__ vmask,
                __bf16* __restrict__ attn_h) {
    __shared__ f32x4 Osh[2][8][64];
    __shared__ float lsh[2][64];

    // XCD-aware swizzle: 2048 blocks, 8 XCDs, 256 contiguous per XCD
    const int orig = blockIdx.x;
    const int bid  = (orig & 7) * 256 + (orig >> 3);

    const int tid = threadIdx.x;
    const int w = tid >> 6, l = tid & 63;
    const int lq = l & 31;
    const int h  = l >> 5;
    const int qb  = bid & 31;
    const int bgh = bid >> 5;
    const int b = bgh >> 4, gh = bgh & 15;
    const int bg = bgh >> 2;
    const int q0 = qb * 32;
    const int ktbeg = w * 4;

    const __bf16* qbase = q_n + ((size_t)bgh * S + q0 + lq) * HD + 8 * h;
    bf16x8 qf[4];
    #pragma unroll
    for (int dc = 0; dc < 4; ++dc) qf[dc] = *(const bf16x8*)(qbase + 16 * dc);

    constexpr float L2E = 1.4426950408889634f;
    const float w0l12 = var_emb[gh] * L2E - 12.5f;
    const float dwl   = (var_emb[16 + gh] - var_emb[gh]) * L2E;
    const float sc2   = SCALE * L2E;

    const __bf16* kfr = kfrag + (size_t)bg * 65536 + (size_t)l * 8;
    const __bf16* vfr = vfrag + (size_t)bg * 65536 + (size_t)l * 8;
    const unsigned long long* mbase = vmask + (size_t)(b << 14) + q0 + lq;

    // preload all 4 masks for this wave's k-tiles (breaks per-tile load chain)
    unsigned long long M[4];
    #pragma unroll
    for (int t = 0; t < 4; ++t)
        M[t] = mbase[(size_t)(ktbeg + t) << 10] >> (4 * h);

    f32x16 OT[2];
    #pragma unroll
    for (int t = 0; t < 2; ++t)
        #pragma unroll
        for (int r = 0; r < 16; ++r) OT[t][r] = 0.0f;
    float lrun = 0.0f;

    // preload K tile ktbeg
    bf16x8 kf[2][4];
    #pragma unroll
    for (int ks = 0; ks < 2; ++ks)
        #pragma unroll
        for (int dc = 0; dc < 4; ++dc)
            kf[ks][dc] = *(const bf16x8*)(kfr + (size_t)(ktbeg * 8 + ks * 4 + dc) * 512);

    #pragma unroll
    for (int ti = 0; ti < 4; ++ti) {
        const int kt = ktbeg + ti;
        // V A-frags for current tile
        bf16x8 vf[2][2][2];
        #pragma unroll
        for (int t = 0; t < 2; ++t)
            #pragma unroll
            for (int ks = 0; ks < 2; ++ks)
                #pragma unroll
                for (int kc = 0; kc < 2; ++kc)
                    vf[t][ks][kc] = *(const bf16x8*)
                        (vfr + (size_t)(((kt * 2 + t) * 2 + ks) * 2 + kc) * 512);

        // swapped QK^T
        f32x16 st[2];
        __builtin_amdgcn_s_setprio(1);
        #pragma unroll
        for (int ks = 0; ks < 2; ++ks) {
            f32x16 acc;
            #pragma unroll
            for (int r = 0; r < 16; ++r) acc[r] = 0.0f;
            #pragma unroll
            for (int dc = 0; dc < 4; ++dc)
                acc = __builtin_amdgcn_mfma_f32_32x32x16_bf16(kf[ks][dc], qf[dc], acc, 0, 0, 0);
            st[ks] = acc;
        }
        __builtin_amdgcn_s_setprio(0);

        // prefetch next K tile
        if (ti < 3) {
            #pragma unroll
            for (int ks = 0; ks < 2; ++ks)
                #pragma unroll
                for (int dc = 0; dc < 4; ++dc)
                    kf[ks][dc] = *(const bf16x8*)(kfr + (size_t)((kt + 1) * 8 + ks * 4 + dc) * 512);
        }

        // P = exp2(st*sc2 + bias - 12.5): no max, no branch, no shuffles
        const unsigned mlo = (unsigned)M[ti];
        const unsigned mhi = (unsigned)(M[ti] >> 32);
        unsigned int u[2][8];
        #pragma unroll
        for (int ks = 0; ks < 2; ++ks) {
            const unsigned wm = ks ? mhi : mlo;
            #pragma unroll
            for (int jj = 0; jj < 8; ++jj) {
                const int r0 = 2 * jj, r1 = 2 * jj + 1;
                const int jr0 = (r0 & 3) + 8 * (r0 >> 2);
                const int jr1 = (r1 & 3) + 8 * (r1 >> 2);
                const float b0 = fmaf((float)((wm >> jr0) & 1u), dwl, w0l12);
                const float b1 = fmaf((float)((wm >> jr1) & 1u), dwl, w0l12);
                const float p0 = exp2f(fmaf(st[ks][r0], sc2, b0));
                const float p1 = exp2f(fmaf(st[ks][r1], sc2, b1));
                lrun += p0 + p1;
                asm("v_cvt_pk_bf16_f32 %0, %1, %2" : "=v"(u[ks][jj]) : "v"(p0), "v"(p1));
            }
        }

        // P redistribution via permlane32_swap -> B-frag words
        uint4 F[2][2];
        #pragma unroll
        for (int ks = 0; ks < 2; ++ks) {
            unsigned a0 = u[ks][0], b0 = u[ks][2];
            unsigned a1 = u[ks][1], b1 = u[ks][3];
            asm("v_permlane32_swap_b32 %0, %1" : "+v"(a0), "+v"(b0));
            asm("v_permlane32_swap_b32 %0, %1" : "+v"(a1), "+v"(b1));
            F[ks][0] = make_uint4(a0, a1, b0, b1);
            unsigned a2 = u[ks][4], b2 = u[ks][6];
            unsigned a3 = u[ks][5], b3 = u[ks][7];
            asm("v_permlane32_swap_b32 %0, %1" : "+v"(a2), "+v"(b2));
            asm("v_permlane32_swap_b32 %0, %1" : "+v"(a3), "+v"(b3));
            F[ks][1] = make_uint4(a2, a3, b2, b3);
        }

        // PV
        __builtin_amdgcn_s_setprio(1);
        #pragma unroll
        for (int t = 0; t < 2; ++t)
            #pragma unroll
            for (int ks = 0; ks < 2; ++ks)
                #pragma unroll
                for (int kc = 0; kc < 2; ++kc)
                    OT[t] = __builtin_amdgcn_mfma_f32_32x32x16_bf16(
                        vf[t][ks][kc], __builtin_bit_cast(bf16x8, F[ks][kc]), OT[t], 0, 0, 0);
        __builtin_amdgcn_s_setprio(0);
    }

    // ---- merge 4 K-quarters: pure sums ----
    if (w & 1) {
        #pragma unroll
        for (int t = 0; t < 2; ++t)
            #pragma unroll
            for (int c = 0; c < 4; ++c)
                Osh[w >> 1][t * 4 + c][l] = (f32x4){OT[t][4 * c], OT[t][4 * c + 1],
                                                    OT[t][4 * c + 2], OT[t][4 * c + 3]};
        lsh[w >> 1][l] = lrun;
    }
    __syncthreads();
    if (!(w & 1)) {
        #pragma unroll
        for (int t = 0; t < 2; ++t)
            #pragma unroll
            for (int c = 0; c < 4; ++c) {
                const f32x4 o = Osh[w >> 1][t * 4 + c][l];
                OT[t][4 * c]     += o[0];
                OT[t][4 * c + 1] += o[1];
                OT[t][4 * c + 2] += o[2];
                OT[t][4 * c + 3] += o[3];
            }
        lrun += lsh[w >> 1][l];
    }
    __syncthreads();
    if (w == 2) {
        #pragma unroll
        for (int t = 0; t < 2; ++t)
            #pragma unroll
            for (int c = 0; c < 4; ++c)
                Osh[0][t * 4 + c][l] = (f32x4){OT[t][4 * c], OT[t][4 * c + 1],
                                               OT[t][4 * c + 2], OT[t][4 * c + 3]};
        lsh[0][l] = lrun;
    }
    __syncthreads();
    if (w != 0) return;

    #pragma unroll
    for (int t = 0; t < 2; ++t)
        #pragma unroll
        for (int c = 0; c < 4; ++c) {
            const f32x4 o = Osh[0][t * 4 + c][l];
            OT[t][4 * c]     += o[0];
            OT[t][4 * c + 1] += o[1];
            OT[t][4 * c + 2] += o[2];
            OT[t][4 * c + 3] += o[3];
        }
    lrun += lsh[0][l];
    lrun += __shfl_xor(lrun, 32);
    const float linv = 1.0f / lrun;

    __bf16* oh = attn_h + (size_t)(b * S + q0 + lq) * DIMM + gh * HD;
    #pragma unroll
    for (int t = 0; t < 2; ++t)
        #pragma unroll
        for (int j = 0; j < 4; ++j) {
            const int d0 = 32 * t + 8 * j + 4 * h;
            unsigned short hv[4];
            #pragma unroll
            for (int c = 0; c < 4; ++c)
                hv[c] = __builtin_bit_cast(unsigned short, (__bf16)(OT[t][4 * j + c] * linv));
            *(ushort4*)(oh + d0) = make_ushort4(hv[0], hv[1], hv[2], hv[3]);
        }
}

extern "C" void kernel_launch(void* const* d_in, const int* in_sizes, int n_in,
                              void* d_out, int out_size, void* d_ws, size_t ws_size,
                              hipStream_t stream) {
    const float* x     = (const float*)d_in[0];
    const float* kv    = (const float*)d_in[1];
    const float* q_w   = (const float*)d_in[2];
    const float* q_b   = (const float*)d_in[3];
    const float* k_w   = (const float*)d_in[4];
    const float* k_b   = (const float*)d_in[5];
    const float* v_w   = (const float*)d_in[6];
    const float* v_b   = (const float*)d_in[7];
    const float* o_w   = (const float*)d_in[8];
    const float* o_b   = (const float*)d_in[9];
    const float* qn_g  = (const float*)d_in[10];
    const float* qn_b  = (const float*)d_in[11];
    const float* kn_g  = (const float*)d_in[12];
    const float* kn_b  = (const float*)d_in[13];
    const float* vemb  = (const float*)d_in[14];
    const int*   qvar  = (const int*)d_in[15];
    const int*   kvar  = (const int*)d_in[16];
    const int*   qtime = (const int*)d_in[17];
    const int*   ktime = (const int*)d_in[18];
    float* out = (float*)d_out;
    char*  W   = (char*)d_ws;

    const size_t MB = 1u << 20;
    __bf16* xh     = (__bf16*)(W);                 // 0-8   (dead after gemm) -> attn_h
    __bf16* kvh    = (__bf16*)(W + 8 * MB);        // 8-16  (dead after gemm) -> vmask
    unsigned long long* vmask = (unsigned long long*)(W + 8 * MB);   // 512KB
    __bf16* q_lin  = (__bf16*)(W + 16 * MB);       // 16-24
    __bf16* kv_lin = (__bf16*)(W + 24 * MB);       // 24-28
    __bf16* q_nb   = (__bf16*)(W + 28 * MB);       // 28-36 (overlays qwh/kvwh/kvb)
    __bf16* qwh    = (__bf16*)(W + 28 * MB);
    __bf16* kvwh   = (__bf16*)(W + 30 * MB);
    float*  kvb    = (float*)(W + 31 * MB);
    __bf16* kfrag  = (__bf16*)(W + 36 * MB);       // 36-38
    __bf16* vfrag  = (__bf16*)(W + 38 * MB);       // 38-40
    __bf16* owh    = (__bf16*)(W + 40 * MB);       // 40-42
    __bf16* owl    = (__bf16*)(W + 42 * MB);       // 42-44
    __bf16* attn_h = xh;

    dim3 blk(256);

    cvt_all<<<5377, blk, 0, stream>>>(x, kv, q_w, k_w, v_w, o_w, k_b, v_b,
                                      xh, kvh, qwh, kvwh, owh, owl, kvb);

    gemm_qkv<<<768, blk, 0, stream>>>(xh, qwh, q_b, q_lin, kvh, kvwh, kvb, kv_lin);

    transforms_all<<<21760, blk, 0, stream>>>(q_lin, kv_lin, qn_g, qn_b, kn_g, kn_b,
                                              qtime, ktime, qvar, kvar,
                                              q_nb, kfrag, vfrag, vmask);

    flash_mfma<<<2048, blk, 0, stream>>>(q_nb, kfrag, vfrag, vemb, vmask, attn_h);

    gemm_o<<<dim3(16, 32), blk, 0, stream>>>(attn_h, owh, owl, o_b, out);
}